// Round 1
// 323.657 us; speedup vs baseline: 1.0228x; 1.0228x over previous
//
#include <hip/hip_runtime.h>
#include <hip/hip_bf16.h>

#define N_NODES 50000
#define N_EDGES 800000
#define NFEAT   8
#define NHID    128
#define NCLASS  112
#define SEG_EPS 1e-16f
#define BN_EPS  1e-5f
#define CAP     64
#define MACRO_TILES 782   // ceil(50000/64)
#define NODE_RANGE 6250   // N_NODES / 8 (one dst-range per XCD)
#define FILL_CHUNK 2048   // edges per block (256 thr x 8)
#define FILL_CHUNKS 391   // ceil(800000 / 2048)
#define ATTN_BLOCKS 3125  // gather_attn grid (x4 iters covers 12500 node-quads)
#define ATTN_ITERS 4
#define Y1_BLOCKS 256     // y1 gemm grid == y1 stat partial count

typedef __hip_bfloat16 bf16;
typedef __attribute__((ext_vector_type(8))) short short8;
typedef __attribute__((ext_vector_type(4))) float f32x4;

__device__ __forceinline__ float bfbits2f(unsigned int lo16) {
    union { unsigned int u; float f; } c; c.u = lo16 << 16; return c.f;
}

__device__ __forceinline__ unsigned int pack_bf2(float a, float b) {
    union { unsigned int u; bf16 h[2]; } t;
    t.h[0] = __float2bfloat16(a);
    t.h[1] = __float2bfloat16(b);
    return t.u;
}

// ============ bucketed CSR build: XCD-range-partitioned scatter ============
// range = blockIdx & 7 -> with round-robin blockIdx->XCD mapping, each dst-range's
// 1.6 MB bucket slice stays in ONE XCD's L2. Edges are read 8x (L2/L3-served).
// dst scan vectorized int4 x2 (8 contiguous edges/thread); arrival order changes
// vs scalar version but the bitonic sort canonicalizes it.
__global__ __launch_bounds__(256)
void k_fill_bucket(const int* __restrict__ src, const int* __restrict__ dst,
                   const float* __restrict__ ewt,
                   int* __restrict__ cnt, unsigned int* __restrict__ bucket) {
    const int range = blockIdx.x & 7;
    const int chunk = blockIdx.x >> 3;
    const int lo = range * NODE_RANGE, hi = lo + NODE_RANGE;
    const int e0 = chunk * FILL_CHUNK + threadIdx.x * 8;
    if (e0 >= N_EDGES) return;            // 800000 % 8 == 0: all-or-nothing per thread
    const int4 d0 = *(const int4*)&dst[e0];
    const int4 d1 = *(const int4*)&dst[e0 + 4];
    const int dd[8] = {d0.x, d0.y, d0.z, d0.w, d1.x, d1.y, d1.z, d1.w};
#pragma unroll
    for (int i = 0; i < 8; i++) {
        int d = dd[i];
        if (d < lo || d >= hi) continue;
        int e = e0 + i;
        int slot = atomicAdd(&cnt[d], 1);
        if (slot < CAP) {
            unsigned int iw = (unsigned int)(ewt[e] * 32767.f + 0.5f);
            bucket[d * CAP + slot] = ((unsigned int)src[e] << 15) | iw;
        }
    }
}

// ====== layer-1 f_src/f_dst (w1proj fused: each block recomputes 16 dots) ======
__global__ __launch_bounds__(256)
void k_fsfd(const float* __restrict__ x, const float* __restrict__ W1,
            const float* __restrict__ a1s, const float* __restrict__ a1d,
            float* __restrict__ fs, float* __restrict__ fd) {
    __shared__ float sw[16];              // [0..7] = w1s, [8..15] = w1d
    const int t = threadIdx.x, w = t >> 6, lane = t & 63;
#pragma unroll
    for (int dd = 0; dd < 4; dd++) {
        int dot = w + dd * 4;             // 0..15 across 4 waves
        int k = dot & 7;
        const float* a = (dot < 8) ? a1s : a1d;
        float v = W1[k * NHID + lane] * a[lane] + W1[k * NHID + 64 + lane] * a[64 + lane];
#pragma unroll
        for (int off = 32; off > 0; off >>= 1) v += __shfl_down(v, off);
        if (lane == 0) sw[dot] = v;
    }
    __syncthreads();
    const int i = blockIdx.x * 256 + t;
    if (i < N_NODES) {
        const float4 x0 = ((const float4*)x)[i * 2];
        const float4 x1 = ((const float4*)x)[i * 2 + 1];
        fs[i] = x0.x*sw[0] + x0.y*sw[1] + x0.z*sw[2] + x0.w*sw[3]
              + x1.x*sw[4] + x1.y*sw[5] + x1.z*sw[6] + x1.w*sw[7];
        fd[i] = x0.x*sw[8] + x0.y*sw[9] + x0.z*sw[10] + x0.w*sw[11]
              + x1.x*sw[12] + x1.y*sw[13] + x1.z*sw[14] + x1.w*sw[15];
    }
}

// ===== canonical sort + layer-1 gather fused: sorted bucket stays in regs =====
// 64-lane bitonic sort per node (deterministic order), write back for later
// gathers, then xaggn[d] = (sum coef*x[src]) / (sum coef + eps) via __shfl pulls.
__global__ __launch_bounds__(256)
void k_sort_gather_x(const int* __restrict__ cnt, unsigned int* __restrict__ bucket,
                     const float* __restrict__ fs, const float* __restrict__ fd,
                     const float* __restrict__ x, float* __restrict__ xaggn) {
    const int d = blockIdx.x * 4 + (threadIdx.x >> 6);
    const int lane = threadIdx.x & 63;
    const int deg = min(cnt[d], CAP);
    unsigned int v = (lane < deg) ? bucket[d * CAP + lane] : 0xFFFFFFFFu;
#pragma unroll
    for (int k = 2; k <= 64; k <<= 1) {
#pragma unroll
        for (int s = k >> 1; s > 0; s >>= 1) {
            unsigned int o = (unsigned int)__shfl_xor((int)v, s);
            bool keepmin = ((lane & s) == 0) == ((lane & k) == 0);
            v = keepmin ? min(v, o) : max(v, o);
        }
    }
    if (lane < deg) bucket[d * CAP + lane] = v;
    // gather: 8 lanes per edge, col = lane&7
    const int col = lane & 7, eslot = lane >> 3;
    const float fdd = fd[d];
    float acc = 0.f, den = 0.f;
    for (int base = 0; base < deg; base += 8) {
        int e = base + eslot;                               // <= 63 always
        unsigned int u = (unsigned int)__shfl((int)v, e);   // sorted entry e
        if (e < deg) {
            int s = u >> 15;
            float f = fs[s] + fdd;
            float lr = f > 0.f ? f : 0.2f * f;
            float c = __expf(-lr);
            den += c;
            acc += c * x[s * NFEAT + col];
        }
    }
#pragma unroll
    for (int off = 8; off < 64; off <<= 1) {
        acc += __shfl_xor(acc, off);
        den += __shfl_xor(den, off);
    }
    if (eslot == 0) xaggn[d * NFEAT + col] = acc / (den + SEG_EPS);
}

// y1(bf16) = xaggn @ W1; per-block stat partials (deterministic)
__global__ __launch_bounds__(256)
void k_y1_gemm(const float* __restrict__ xaggn, const float* __restrict__ W1,
               bf16* __restrict__ y1, float* __restrict__ Psum, float* __restrict__ Psq) {
    int t = threadIdx.x;
    int r = t >> 7, j = t & 127;
    float w[NFEAT];
#pragma unroll
    for (int k = 0; k < NFEAT; k++) w[k] = W1[k * NHID + j];
    float ls = 0.f, lq = 0.f;
    for (int row = blockIdx.x * 2 + r; row < N_NODES; row += gridDim.x * 2) {
        const float4 x0 = ((const float4*)xaggn)[row * 2];
        const float4 x1 = ((const float4*)xaggn)[row * 2 + 1];
        float v = x0.x*w[0] + x0.y*w[1] + x0.z*w[2] + x0.w*w[3]
                + x1.x*w[4] + x1.y*w[5] + x1.z*w[6] + x1.w*w[7];
        y1[(size_t)row * NHID + j] = __float2bfloat16(v);
        ls += v; lq += v * v;
    }
    __shared__ float sbuf[256];
    sbuf[t] = ls; __syncthreads();
    if (r == 0) Psum[blockIdx.x * 128 + j] = sbuf[j] + sbuf[j + 128];
    __syncthreads();
    sbuf[t] = lq; __syncthreads();
    if (r == 0) Psq[blockIdx.x * 128 + j] = sbuf[j] + sbuf[j + 128];
}

// single-block full BN reduce for the y1 path (256 partials -> scale/shift)
__global__ __launch_bounds__(512)
void k_reduce_full(const float* __restrict__ Psum, const float* __restrict__ Psq,
                   const float* __restrict__ gamma, const float* __restrict__ beta,
                   float* __restrict__ scale, float* __restrict__ shift) {
    int j = threadIdx.x & 127;
    int g = threadIdx.x >> 7;             // 4 groups x 64 partials
    float s = 0.f, q = 0.f;
#pragma unroll 8
    for (int b = g * 64; b < g * 64 + 64; b++) {
        s += Psum[b * 128 + j];
        q += Psq[b * 128 + j];
    }
    __shared__ float Ls[4][128], Lq[4][128];
    Ls[g][j] = s; Lq[g][j] = q;
    __syncthreads();
    if (g == 0) {
        float st = ((Ls[0][j] + Ls[1][j]) + Ls[2][j]) + Ls[3][j];
        float qt = ((Lq[0][j] + Lq[1][j]) + Lq[2][j]) + Lq[3][j];
        float mu = st * (1.f / N_NODES);
        float var = qt * (1.f / N_NODES) - mu * mu;
        float rs = rsqrtf(var + BN_EPS);
        float ga = gamma[j];
        scale[j] = rs * ga;
        shift[j] = beta[j] - mu * rs * ga;
    }
}

// ---- deterministic two-stage partial reduction (y2 path) ----
__global__ __launch_bounds__(256)
void k_reduce_a(const float* __restrict__ Psum, const float* __restrict__ Psq,
                int nIn, int chunk,
                float* __restrict__ Qsum, float* __restrict__ Qsq) {
    int j = threadIdx.x & 127;
    int h = threadIdx.x >> 7;
    int u = blockIdx.x * 2 + h;
    int b0 = u * chunk, b1 = min(b0 + chunk, nIn);
    float s = 0.f, q = 0.f;
#pragma unroll 8
    for (int b = b0; b < b1; b++) {
        s += Psum[b * 128 + j];
        q += Psq[b * 128 + j];
    }
    Qsum[u * 128 + j] = s;
    Qsq[u * 128 + j] = q;
}

__global__ __launch_bounds__(512)
void k_reduce_b(const float* __restrict__ Qsum, const float* __restrict__ Qsq,
                const float* __restrict__ gamma, const float* __restrict__ beta,
                float* __restrict__ scale, float* __restrict__ shift) {
    int j = threadIdx.x & 127;
    int g = threadIdx.x >> 7;
    float s = 0.f, q = 0.f;
#pragma unroll
    for (int u = g * 8; u < g * 8 + 8; u++) {
        s += Qsum[u * 128 + j];
        q += Qsq[u * 128 + j];
    }
    __shared__ float Ls[4][128], Lq[4][128];
    Ls[g][j] = s; Lq[g][j] = q;
    __syncthreads();
    if (g == 0) {
        float st = ((Ls[0][j] + Ls[1][j]) + Ls[2][j]) + Ls[3][j];
        float qt = ((Lq[0][j] + Lq[1][j]) + Lq[2][j]) + Lq[3][j];
        float mu = st * (1.f / N_NODES);
        float var = qt * (1.f / N_NODES) - mu * mu;
        float rs = rsqrtf(var + BN_EPS);
        float ga = gamma[j];
        scale[j] = rs * ga;
        shift[j] = beta[j] - mu * rs * ga;
    }
}

// w2s = W2 @ a_s, w2d = W2 @ a_d  ([128] each)
__global__ void k_w2proj(const float* __restrict__ W2,
                         const float* __restrict__ as_, const float* __restrict__ ad_,
                         float* __restrict__ ws_, float* __restrict__ wd_) {
    int k = blockIdx.x, n = threadIdx.x;   // 128 x 128
    float w = W2[k * NHID + n];
    float vs = w * as_[n], vd = w * ad_[n];
#pragma unroll
    for (int off = 32; off > 0; off >>= 1) { vs += __shfl_down(vs, off); vd += __shfl_down(vd, off); }
    __shared__ float ps[2], pd[2];
    if ((n & 63) == 0) { ps[n >> 6] = vs; pd[n >> 6] = vd; }
    __syncthreads();
    if (n == 0) { ws_[k] = ps[0] + ps[1]; wd_[k] = pd[0] + pd[1]; }
}

// ===== MFMA GEMM: hout[N,NCV](bf16) = lrelu(bn(Yb[N,128])) @ W[128,NCV] =====
// ATT: attention projections fs/fd computed by ONE extra MFMA tile with a
// register-resident B-fragment [w2s | w2d | 0...] (lanes m16<2 supply the two
// real columns) instead of 192 cross-lane shuffles per thread in staging.
template<int NCV, bool ATT>
__global__ __launch_bounds__(256)
void k_gemm_mfma(const bf16* __restrict__ Yin,
                 const float* __restrict__ scale, const float* __restrict__ shift,
                 const float* __restrict__ W,
                 bf16* __restrict__ hout,
                 const float* __restrict__ w2s, const float* __restrict__ w2d,
                 float* __restrict__ fs, float* __restrict__ fd) {
    constexpr int NT = NCV / 16;
    __shared__ bf16 Wt[NCV * 136];   // W^T, [n][k]
    __shared__ bf16 At[64 * 136];
    const int t = threadIdx.x;
    for (int idx = t; idx < 128 * NCV; idx += 256) {
        int k = idx / NCV, n = idx - k * NCV;
        Wt[n * 136 + k] = __float2bfloat16(W[idx]);
    }
    const int p  = t & 63;          // feature-pair index (lane)
    const int rg = t >> 6;          // wave id / staging row group
    const float sc0 = scale[2*p],   sh0 = shift[2*p];
    const float sc1 = scale[2*p+1], sh1 = shift[2*p+1];
    const int lane = t & 63;
    const int m16 = lane & 15;
    const int g = lane >> 4;        // quad 0..3
    // mt-invariant attention B-fragments (bf16, in registers)
    short8 attb[4];
    if constexpr (ATT) {
#pragma unroll
        for (int kk = 0; kk < 4; kk++) {
            union { short8 s; unsigned int u[4]; } pk;
            if (m16 < 2) {
                const float* wv = (m16 == 0) ? w2s : w2d;
                const float4 f0 = *(const float4*)&wv[kk * 32 + g * 8];
                const float4 f1 = *(const float4*)&wv[kk * 32 + g * 8 + 4];
                pk.u[0] = pack_bf2(f0.x, f0.y);
                pk.u[1] = pack_bf2(f0.z, f0.w);
                pk.u[2] = pack_bf2(f1.x, f1.y);
                pk.u[3] = pack_bf2(f1.z, f1.w);
            } else {
                pk.u[0] = pk.u[1] = pk.u[2] = pk.u[3] = 0u;
            }
            attb[kk] = pk.s;
        }
    }
    __syncthreads();

    for (int mt = blockIdx.x; mt < MACRO_TILES; mt += gridDim.x) {
        const int row0 = mt * 64;
#pragma unroll
        for (int i2 = 0; i2 < 16; i2++) {
            int row = rg + i2 * 4;
            int grow = row0 + row;
            unsigned int u = (grow < N_NODES) ? ((const unsigned int*)Yin)[(size_t)grow * 64 + p] : 0u;
            float v0 = bfbits2f(u & 0xFFFF) * sc0 + sh0; v0 = v0 > 0.f ? v0 : 0.01f * v0;
            float v1 = bfbits2f(u >> 16)    * sc1 + sh1; v1 = v1 > 0.f ? v1 : 0.01f * v1;
            *(unsigned int*)&At[row * 136 + 2 * p] = pack_bf2(v0, v1);
        }
        __syncthreads();
        f32x4 acc[NT];
#pragma unroll
        for (int c = 0; c < NT; c++) acc[c] = (f32x4){0.f, 0.f, 0.f, 0.f};
        f32x4 accA = (f32x4){0.f, 0.f, 0.f, 0.f};
#pragma unroll
        for (int kk = 0; kk < 4; kk++) {
            short8 af = *(const short8*)&At[(rg * 16 + m16) * 136 + kk * 32 + g * 8];
#pragma unroll
            for (int c = 0; c < NT; c++) {
                short8 bfr = *(const short8*)&Wt[(c * 16 + m16) * 136 + kk * 32 + g * 8];
                acc[c] = __builtin_amdgcn_mfma_f32_16x16x32_bf16(af, bfr, acc[c], 0, 0, 0);
            }
            if constexpr (ATT)
                accA = __builtin_amdgcn_mfma_f32_16x16x32_bf16(af, attb[kk], accA, 0, 0, 0);
        }
        const int orow = row0 + rg * 16 + g * 4;
#pragma unroll
        for (int c = 0; c < NT; c++) {
#pragma unroll
            for (int r = 0; r < 4; r++) {
                int grow = orow + r;
                if (grow < N_NODES)
                    hout[(size_t)grow * NCV + c * 16 + m16] = __float2bfloat16(acc[c][r]);
            }
        }
        if constexpr (ATT) {
            if (m16 < 2) {
                float* o = (m16 == 0) ? fs : fd;
#pragma unroll
                for (int r = 0; r < 4; r++) {
                    int grow = orow + r;
                    if (grow < N_NODES) o[grow] = accA[r];
                }
            }
        }
        __syncthreads();
    }
}

// attention gather + fused BN stat partials: 4 nodes/block-iter, grid-strided
// (3125 blocks x 4 iters). LDS per wave is wave-private -> no in-loop barriers.
__global__ __launch_bounds__(256)
void k_gather_attn_bf(const int* __restrict__ cnt, const unsigned int* __restrict__ bucket,
                      const float* __restrict__ fs, const float* __restrict__ fd,
                      const bf16* __restrict__ h, bf16* __restrict__ y,
                      float* __restrict__ Psum, float* __restrict__ Psq) {
    const int q = threadIdx.x >> 6;       // node sub-block 0..3
    const int j = threadIdx.x & 63;       // feature pair
    __shared__ int s_idx[4][CAP];
    __shared__ float s_e[4][CAP];
    __shared__ float red[4][64][2];
    float ls0 = 0.f, ls1 = 0.f, lq0 = 0.f, lq1 = 0.f;
    for (int it = 0; it < ATTN_ITERS; it++) {
        const int d = (blockIdx.x + it * ATTN_BLOCKS) * 4 + q;
        const int deg = min(cnt[d], CAP);
        const float fdd = fd[d];
        if (j < deg) {
            int s = bucket[d * CAP + j] >> 15;
            float f = fs[s] + fdd;
            float lr = f > 0.f ? f : 0.2f * f;
            s_idx[q][j] = s;
            s_e[q][j] = __expf(-lr);
        }
        float n0 = 0.f, n1 = 0.f, den = 0.f;
#pragma unroll 4
        for (int k = 0; k < deg; k++) {
            float e = s_e[q][k];                       // wave-broadcast (free)
            unsigned int u = *(const unsigned int*)&h[(size_t)s_idx[q][k] * NHID + 2 * j];
            den += e;
            n0 += e * bfbits2f(u & 0xFFFF);
            n1 += e * bfbits2f(u >> 16);
        }
        float rsd = 1.f / (den + SEG_EPS);
        float v0 = n0 * rsd, v1 = n1 * rsd;
        ((unsigned int*)y)[(size_t)d * 64 + j] = pack_bf2(v0, v1);
        ls0 += v0; lq0 += v0 * v0;
        ls1 += v1; lq1 += v1 * v1;
    }
    red[q][j][0] = ls0; red[q][j][1] = ls1;
    __syncthreads();
    if (q == 0) {
        float a0 = ((red[0][j][0] + red[1][j][0]) + red[2][j][0]) + red[3][j][0];
        float a1 = ((red[0][j][1] + red[1][j][1]) + red[2][j][1]) + red[3][j][1];
        Psum[blockIdx.x * 128 + 2 * j]     = a0;
        Psum[blockIdx.x * 128 + 2 * j + 1] = a1;
    }
    __syncthreads();
    red[q][j][0] = lq0; red[q][j][1] = lq1;
    __syncthreads();
    if (q == 0) {
        float a0 = ((red[0][j][0] + red[1][j][0]) + red[2][j][0]) + red[3][j][0];
        float a1 = ((red[0][j][1] + red[1][j][1]) + red[2][j][1]) + red[3][j][1];
        Psq[blockIdx.x * 128 + 2 * j]     = a0;
        Psq[blockIdx.x * 128 + 2 * j + 1] = a1;
    }
}

// final gather + epilogue: 4 nodes/block, 64 thr/node, 2 feats per thread (j<56)
__global__ __launch_bounds__(256)
void k_gather_out_bf(const int* __restrict__ cnt, const unsigned int* __restrict__ bucket,
                     const bf16* __restrict__ sup, const float* __restrict__ bg,
                     float* __restrict__ out) {
    int q = threadIdx.x >> 6;
    int j = threadIdx.x & 63;
    int d = blockIdx.x * 4 + q;
    __shared__ int s_idx[4][CAP];
    __shared__ float s_w[4][CAP];
    int deg = min(cnt[d], CAP);
    if (j < deg) {
        unsigned int b = bucket[d * CAP + j];
        s_idx[q][j] = b >> 15;
        s_w[q][j] = (float)(b & 0x7FFF) * (1.f / (32767.f * 3.f));
    }
    __syncthreads();
    if (j >= NCLASS / 2) return;    // 56 active pairs
    float a0 = 0.f, a1 = 0.f;
#pragma unroll 4
    for (int k = 0; k < deg; k++) {
        float w = s_w[q][k];
        unsigned int u = *(const unsigned int*)&sup[(size_t)s_idx[q][k] * NCLASS + 2 * j];
        a0 += w * bfbits2f(u & 0xFFFF);
        a1 += w * bfbits2f(u >> 16);
    }
    unsigned int us = *(const unsigned int*)&sup[(size_t)d * NCLASS + 2 * j];
    float2 o;
    o.x = a0 + bfbits2f(us & 0xFFFF) * (2.f / 3.f) + bg[2 * j];
    o.y = a1 + bfbits2f(us >> 16)    * (2.f / 3.f) + bg[2 * j + 1];
    *(float2*)&out[(size_t)d * NCLASS + 2 * j] = o;
}

extern "C" void kernel_launch(void* const* d_in, const int* in_sizes, int n_in,
                              void* d_out, int out_size, void* d_ws, size_t ws_size,
                              hipStream_t stream) {
    const float* x    = (const float*)d_in[0];
    const int*   ei   = (const int*)d_in[1];
    const float* ewt  = (const float*)d_in[2];
    const float* W1   = (const float*)d_in[3];
    const float* a1s  = (const float*)d_in[4];
    const float* a1d  = (const float*)d_in[5];
    const float* W2   = (const float*)d_in[6];
    const float* a2s  = (const float*)d_in[7];
    const float* a2d  = (const float*)d_in[8];
    const float* gam  = (const float*)d_in[9];
    const float* bet  = (const float*)d_in[10];
    const float* Wg   = (const float*)d_in[11];
    const float* bg   = (const float*)d_in[12];
    float* out = (float*)d_out;

    const int* src = ei;
    const int* dst = ei + N_EDGES;

    float* ws    = (float*)d_ws;
    bf16*  Yb    = (bf16*)ws;                       // [N,128] bf16 (y1, then y2)
    bf16*  Hb    = (bf16*)(ws + 3203072);           // [N,128] bf16 (h2 / support)
    unsigned int* bucket = (unsigned int*)(ws + 6403072);   // [N*64] packed
    float* xagg  = ws + 9603072;                    // [N,8]
    float* fs    = ws + 10003072;                   // [N]
    float* fd    = ws + 10053072;                   // [N]
    int*   cnt   = (int*)(ws + 10103072);           // [N]
    float* scale = ws + 10153072;                   // [128]
    float* shift = scale + 128;                     // [128]
    float* w2s   = shift + 128;                     // [128]
    float* w2d   = w2s + 128;                       // [128]
    float* Psum  = ws + 10153600;                   // [3125][128]
    float* Psq   = Psum + 400000;                   // [3125][128]
    float* Qsum  = Psq + 400000;                    // [32][128]
    float* Qsq   = Qsum + 4096;                     // [32][128]

    // ---- bucketed CSR build (XCD-partitioned) ----
    hipMemsetAsync(cnt, 0, (size_t)N_NODES * 4, stream);
    k_fill_bucket<<<FILL_CHUNKS * 8, 256, 0, stream>>>(src, dst, ewt, cnt, bucket);

    // ---- layer 1 (linearity-restructured; sort fused into gather) ----
    k_fsfd<<<(N_NODES + 255) / 256, 256, 0, stream>>>(x, W1, a1s, a1d, fs, fd);
    k_sort_gather_x<<<N_NODES / 4, 256, 0, stream>>>(cnt, bucket, fs, fd, x, xagg);
    k_y1_gemm<<<Y1_BLOCKS, 256, 0, stream>>>(xagg, W1, Yb, Psum, Psq);
    k_reduce_full<<<1, 512, 0, stream>>>(Psum, Psq, gam, bet, scale, shift);

    // ---- layer 2 (att projections via extra MFMA tile) ----
    k_w2proj<<<128, 128, 0, stream>>>(W2, a2s, a2d, w2s, w2d);
    k_gemm_mfma<128, true><<<MACRO_TILES, 256, 0, stream>>>(Yb, scale, shift, W2, Hb,
                                                            w2s, w2d, fs, fd);      // Hb = h2
    k_gather_attn_bf<<<ATTN_BLOCKS, 256, 0, stream>>>(cnt, bucket, fs, fd, Hb, Yb,
                                                      Psum, Psq);                   // Yb = y2 + stats
    k_reduce_a<<<16, 256, 0, stream>>>(Psum, Psq, ATTN_BLOCKS, 98, Qsum, Qsq);
    k_reduce_b<<<1, 512, 0, stream>>>(Qsum, Qsq, gam, bet, scale, shift);

    // ---- output head ----
    k_gemm_mfma<112, false><<<MACRO_TILES, 256, 0, stream>>>(Yb, scale, shift, Wg, Hb,
                                                             nullptr, nullptr, nullptr, nullptr);
    k_gather_out_bf<<<N_NODES / 4, 256, 0, stream>>>(cnt, bucket, Hb, bg, out);
}

// Round 2
// 319.764 us; speedup vs baseline: 1.0353x; 1.0122x over previous
//
#include <hip/hip_runtime.h>
#include <hip/hip_bf16.h>

#define N_NODES 50000
#define N_EDGES 800000
#define NFEAT   8
#define NHID    128
#define NCLASS  112
#define SEG_EPS 1e-16f
#define BN_EPS  1e-5f
#define CAP     64
#define MACRO_TILES 782   // ceil(50000/64)
#define NODE_RANGE 6250   // N_NODES / 8 (one dst-range per XCD)
#define FILL_CHUNK 2048   // edges per block (256 thr x 8)
#define FILL_CHUNKS 391   // ceil(800000 / 2048)
#define FSFD_BLOCKS 196   // ceil(50000/256)
#define GATH_GRID 12800   // 8 XCDs x 1600 blocks (4 node-slots each, 6400 >= 6250)
#define ATT_GRID 3200     // 8 XCDs x 400 blocks
#define ATT_IT 4          // 400*4 = 1600 quad-slots per range
#define Y1_BLOCKS 256     // y1 gemm grid == y1 stat partial count

typedef __hip_bfloat16 bf16;
typedef __attribute__((ext_vector_type(8))) short short8;
typedef __attribute__((ext_vector_type(4))) float f32x4;
typedef __attribute__((ext_vector_type(4))) unsigned int u32x4;

__device__ __forceinline__ float bfbits2f(unsigned int lo16) {
    union { unsigned int u; float f; } c; c.u = lo16 << 16; return c.f;
}

__device__ __forceinline__ unsigned int pack_bf2(float a, float b) {
    union { unsigned int u; bf16 h[2]; } t;
    t.h[0] = __float2bfloat16(a);
    t.h[1] = __float2bfloat16(b);
    return t.u;
}

// ============ bucketed CSR build (XCD-partitioned) + fused fsfd ============
// blocks [0, FILL_CHUNKS*8): scatter edges into per-dst bucket, range = blockIdx&7
// keeps each 1.6MB bucket slice in one XCD's L2. blocks >= FILL_CHUNKS*8: layer-1
// f_src/f_dst projections (independent work, saves a launch).
__global__ __launch_bounds__(256)
void k_fill_fsfd(const int* __restrict__ src, const int* __restrict__ dst,
                 const float* __restrict__ ewt,
                 int* __restrict__ cnt, unsigned int* __restrict__ bucket,
                 const float* __restrict__ x, const float* __restrict__ W1,
                 const float* __restrict__ a1s, const float* __restrict__ a1d,
                 float* __restrict__ fs, float* __restrict__ fd) {
    if (blockIdx.x < FILL_CHUNKS * 8) {
        const int range = blockIdx.x & 7;
        const int chunk = blockIdx.x >> 3;
        const int lo = range * NODE_RANGE, hi = lo + NODE_RANGE;
        const int e0 = chunk * FILL_CHUNK + threadIdx.x * 8;
        if (e0 >= N_EDGES) return;        // 800000 % 8 == 0: all-or-nothing per thread
        const int4 d0 = *(const int4*)&dst[e0];
        const int4 d1 = *(const int4*)&dst[e0 + 4];
        const int dd[8] = {d0.x, d0.y, d0.z, d0.w, d1.x, d1.y, d1.z, d1.w};
#pragma unroll
        for (int i = 0; i < 8; i++) {
            int d = dd[i];
            if (d < lo || d >= hi) continue;
            int e = e0 + i;
            int slot = atomicAdd(&cnt[d], 1);
            if (slot < CAP) {
                unsigned int iw = (unsigned int)(ewt[e] * 32767.f + 0.5f);
                bucket[d * CAP + slot] = ((unsigned int)src[e] << 15) | iw;
            }
        }
        return;
    }
    // ---- fsfd part ----
    __shared__ float sw[16];              // [0..7] = w1s, [8..15] = w1d
    const int t = threadIdx.x, w = t >> 6, lane = t & 63;
#pragma unroll
    for (int dd = 0; dd < 4; dd++) {
        int dot = w + dd * 4;
        int k = dot & 7;
        const float* a = (dot < 8) ? a1s : a1d;
        float v = W1[k * NHID + lane] * a[lane] + W1[k * NHID + 64 + lane] * a[64 + lane];
#pragma unroll
        for (int off = 32; off > 0; off >>= 1) v += __shfl_down(v, off);
        if (lane == 0) sw[dot] = v;
    }
    __syncthreads();
    const int i = (blockIdx.x - FILL_CHUNKS * 8) * 256 + t;
    if (i < N_NODES) {
        const float4 x0 = ((const float4*)x)[i * 2];
        const float4 x1 = ((const float4*)x)[i * 2 + 1];
        fs[i] = x0.x*sw[0] + x0.y*sw[1] + x0.z*sw[2] + x0.w*sw[3]
              + x1.x*sw[4] + x1.y*sw[5] + x1.z*sw[6] + x1.w*sw[7];
        fd[i] = x0.x*sw[8] + x0.y*sw[9] + x0.z*sw[10] + x0.w*sw[11]
              + x1.x*sw[12] + x1.y*sw[13] + x1.z*sw[14] + x1.w*sw[15];
    }
}

// ===== canonical sort + layer-1 gather: XCD-aligned nodes, float4 gather =====
// block -> XCD-matched dst range so the just-filled bucket slice is an L2 hit.
// gather: 2 lanes/edge x float4 (32 edges per wave-iteration).
__global__ __launch_bounds__(256)
void k_sort_gather_x(const int* __restrict__ cnt, unsigned int* __restrict__ bucket,
                     const float* __restrict__ fs, const float* __restrict__ fd,
                     const float* __restrict__ x, float* __restrict__ xaggn) {
    const int xcd = blockIdx.x & 7;
    const int wb  = blockIdx.x >> 3;                  // 0..1599
    const int ni  = wb * 4 + (threadIdx.x >> 6);      // node-in-range (wave-uniform)
    if (ni >= NODE_RANGE) return;
    const int d = xcd * NODE_RANGE + ni;
    const int lane = threadIdx.x & 63;
    const int deg = min(cnt[d], CAP);
    unsigned int v = (lane < deg) ? bucket[d * CAP + lane] : 0xFFFFFFFFu;
#pragma unroll
    for (int k = 2; k <= 64; k <<= 1) {
#pragma unroll
        for (int s = k >> 1; s > 0; s >>= 1) {
            unsigned int o = (unsigned int)__shfl_xor((int)v, s);
            bool keepmin = ((lane & s) == 0) == ((lane & k) == 0);
            v = keepmin ? min(v, o) : max(v, o);
        }
    }
    if (lane < deg) bucket[d * CAP + lane] = v;
    // gather: 32 edge-slots x 2 feat-halves
    const int epair = lane >> 1;
    const int half  = lane & 1;
    const float fdd = fd[d];
    float4 acc = {0.f, 0.f, 0.f, 0.f};
    float den = 0.f;
    for (int base = 0; base < deg; base += 32) {
        int e = base + epair;                              // <= 63 always
        unsigned int u = (unsigned int)__shfl((int)v, e);  // sorted entry e
        if (e < deg) {
            int s = u >> 15;
            float f = fs[s] + fdd;
            float lr = f > 0.f ? f : 0.2f * f;
            float c = __expf(-lr);
            if (half == 0) den += c;
            const float4 xv = *(const float4*)&x[s * NFEAT + half * 4];
            acc.x += c * xv.x; acc.y += c * xv.y; acc.z += c * xv.z; acc.w += c * xv.w;
        }
    }
#pragma unroll
    for (int off = 2; off < 64; off <<= 1) {
        acc.x += __shfl_xor(acc.x, off);
        acc.y += __shfl_xor(acc.y, off);
        acc.z += __shfl_xor(acc.z, off);
        acc.w += __shfl_xor(acc.w, off);
        den   += __shfl_xor(den, off);
    }
    den += __shfl_xor(den, 1);   // odd lanes had 0
    if (lane < 2) {
        float r = 1.f / (den + SEG_EPS);
        float4 o;
        o.x = acc.x * r; o.y = acc.y * r; o.z = acc.z * r; o.w = acc.w * r;
        *(float4*)&xaggn[d * NFEAT + half * 4] = o;
    }
}

// y1(bf16) = xaggn @ W1; per-block stat partials (deterministic)
__global__ __launch_bounds__(256)
void k_y1_gemm(const float* __restrict__ xaggn, const float* __restrict__ W1,
               bf16* __restrict__ y1, float* __restrict__ Psum, float* __restrict__ Psq) {
    int t = threadIdx.x;
    int r = t >> 7, j = t & 127;
    float w[NFEAT];
#pragma unroll
    for (int k = 0; k < NFEAT; k++) w[k] = W1[k * NHID + j];
    float ls = 0.f, lq = 0.f;
    for (int row = blockIdx.x * 2 + r; row < N_NODES; row += gridDim.x * 2) {
        const float4 x0 = ((const float4*)xaggn)[row * 2];
        const float4 x1 = ((const float4*)xaggn)[row * 2 + 1];
        float v = x0.x*w[0] + x0.y*w[1] + x0.z*w[2] + x0.w*w[3]
                + x1.x*w[4] + x1.y*w[5] + x1.z*w[6] + x1.w*w[7];
        y1[(size_t)row * NHID + j] = __float2bfloat16(v);
        ls += v; lq += v * v;
    }
    __shared__ float sbuf[256];
    sbuf[t] = ls; __syncthreads();
    if (r == 0) Psum[blockIdx.x * 128 + j] = sbuf[j] + sbuf[j + 128];
    __syncthreads();
    sbuf[t] = lq; __syncthreads();
    if (r == 0) Psq[blockIdx.x * 128 + j] = sbuf[j] + sbuf[j + 128];
}

// block 0: full BN reduce (256 y1 partials -> scale/shift); blocks 1..32: w2proj
__global__ __launch_bounds__(512)
void k_bn_w2(const float* __restrict__ Psum, const float* __restrict__ Psq,
             const float* __restrict__ gamma, const float* __restrict__ beta,
             float* __restrict__ scale, float* __restrict__ shift,
             const float* __restrict__ W2,
             const float* __restrict__ as_, const float* __restrict__ ad_,
             float* __restrict__ ws_, float* __restrict__ wd_) {
    const int t = threadIdx.x;
    if (blockIdx.x == 0) {
        int j = t & 127;
        int g = t >> 7;
        float s = 0.f, q = 0.f;
#pragma unroll 8
        for (int b = g * 64; b < g * 64 + 64; b++) {
            s += Psum[b * 128 + j];
            q += Psq[b * 128 + j];
        }
        __shared__ float Ls[4][128], Lq[4][128];
        Ls[g][j] = s; Lq[g][j] = q;
        __syncthreads();
        if (g == 0) {
            float st = ((Ls[0][j] + Ls[1][j]) + Ls[2][j]) + Ls[3][j];
            float qt = ((Lq[0][j] + Lq[1][j]) + Lq[2][j]) + Lq[3][j];
            float mu = st * (1.f / N_NODES);
            float var = qt * (1.f / N_NODES) - mu * mu;
            float rs = rsqrtf(var + BN_EPS);
            float ga = gamma[j];
            scale[j] = rs * ga;
            shift[j] = beta[j] - mu * rs * ga;
        }
        return;
    }
    // w2proj: k = (b-1)*4 + (t>>7), n = t&127
    const int k = (blockIdx.x - 1) * 4 + (t >> 7);
    const int n = t & 127;
    float wv = W2[k * NHID + n];
    float vs = wv * as_[n], vd = wv * ad_[n];
#pragma unroll
    for (int off = 32; off > 0; off >>= 1) { vs += __shfl_down(vs, off); vd += __shfl_down(vd, off); }
    __shared__ float ps[8], pd[8];
    const int wid = t >> 6;
    if ((t & 63) == 0) { ps[wid] = vs; pd[wid] = vd; }
    __syncthreads();
    if ((t & 127) == 0) { ws_[k] = ps[wid] + ps[wid + 1]; wd_[k] = pd[wid] + pd[wid + 1]; }
}

// ---- deterministic two-stage partial reduction (y2 path) ----
__global__ __launch_bounds__(256)
void k_reduce_a(const float* __restrict__ Psum, const float* __restrict__ Psq,
                int nIn, int chunk,
                float* __restrict__ Qsum, float* __restrict__ Qsq) {
    int j = threadIdx.x & 127;
    int h = threadIdx.x >> 7;
    int u = blockIdx.x * 2 + h;
    int b0 = u * chunk, b1 = min(b0 + chunk, nIn);
    float s = 0.f, q = 0.f;
#pragma unroll 8
    for (int b = b0; b < b1; b++) {
        s += Psum[b * 128 + j];
        q += Psq[b * 128 + j];
    }
    Qsum[u * 128 + j] = s;
    Qsq[u * 128 + j] = q;
}

__global__ __launch_bounds__(512)
void k_reduce_b(const float* __restrict__ Qsum, const float* __restrict__ Qsq,
                const float* __restrict__ gamma, const float* __restrict__ beta,
                float* __restrict__ scale, float* __restrict__ shift) {
    int j = threadIdx.x & 127;
    int g = threadIdx.x >> 7;
    float s = 0.f, q = 0.f;
#pragma unroll
    for (int u = g * 8; u < g * 8 + 8; u++) {
        s += Qsum[u * 128 + j];
        q += Qsq[u * 128 + j];
    }
    __shared__ float Ls[4][128], Lq[4][128];
    Ls[g][j] = s; Lq[g][j] = q;
    __syncthreads();
    if (g == 0) {
        float st = ((Ls[0][j] + Ls[1][j]) + Ls[2][j]) + Ls[3][j];
        float qt = ((Lq[0][j] + Lq[1][j]) + Lq[2][j]) + Lq[3][j];
        float mu = st * (1.f / N_NODES);
        float var = qt * (1.f / N_NODES) - mu * mu;
        float rs = rsqrtf(var + BN_EPS);
        float ga = gamma[j];
        scale[j] = rs * ga;
        shift[j] = beta[j] - mu * rs * ga;
    }
}

// ===== MFMA GEMM: hout[N,OSTRIDE](bf16) = lrelu(bn(Yb[N,128])) @ W[128,NCV] =====
// Staging vectorized: fixed 8-feat chunk per thread, dwordx4 loads + ds_write_b128,
// BN scale/shift in 16 regs. ATT: fs/fd via one extra register-B MFMA tile.
template<int NCV, int OSTRIDE, bool ATT>
__global__ __launch_bounds__(256)
void k_gemm_mfma(const bf16* __restrict__ Yin,
                 const float* __restrict__ scale, const float* __restrict__ shift,
                 const float* __restrict__ W,
                 bf16* __restrict__ hout,
                 const float* __restrict__ w2s, const float* __restrict__ w2d,
                 float* __restrict__ fs, float* __restrict__ fd) {
    constexpr int NT = NCV / 16;
    constexpr int NC4 = NCV / 4;
    __shared__ bf16 Wt[NCV * 136];   // W^T, [n][k]
    __shared__ bf16 At[64 * 136];
    const int t = threadIdx.x;
    for (int idx = t; idx < 128 * NC4; idx += 256) {
        int k = idx / NC4, n4 = (idx - k * NC4) * 4;
        const float4 wv = *(const float4*)&W[k * NCV + n4];
        Wt[(n4 + 0) * 136 + k] = __float2bfloat16(wv.x);
        Wt[(n4 + 1) * 136 + k] = __float2bfloat16(wv.y);
        Wt[(n4 + 2) * 136 + k] = __float2bfloat16(wv.z);
        Wt[(n4 + 3) * 136 + k] = __float2bfloat16(wv.w);
    }
    const int chunk = t & 15;       // fixed 8-feat chunk
    const int rgrp  = t >> 4;       // staging row group 0..15
    float sc[8], sh[8];
    {
        const float4 s0 = *(const float4*)&scale[chunk * 8];
        const float4 s1 = *(const float4*)&scale[chunk * 8 + 4];
        const float4 h0 = *(const float4*)&shift[chunk * 8];
        const float4 h1 = *(const float4*)&shift[chunk * 8 + 4];
        sc[0]=s0.x; sc[1]=s0.y; sc[2]=s0.z; sc[3]=s0.w;
        sc[4]=s1.x; sc[5]=s1.y; sc[6]=s1.z; sc[7]=s1.w;
        sh[0]=h0.x; sh[1]=h0.y; sh[2]=h0.z; sh[3]=h0.w;
        sh[4]=h1.x; sh[5]=h1.y; sh[6]=h1.z; sh[7]=h1.w;
    }
    const int lane = t & 63;
    const int m16 = lane & 15;
    const int g = lane >> 4;        // quad 0..3
    const int rg = t >> 6;          // wave id
    short8 attb[4];
    if constexpr (ATT) {
#pragma unroll
        for (int kk = 0; kk < 4; kk++) {
            union { short8 s; unsigned int u[4]; } pk;
            if (m16 < 2) {
                const float* wv = (m16 == 0) ? w2s : w2d;
                const float4 f0 = *(const float4*)&wv[kk * 32 + g * 8];
                const float4 f1 = *(const float4*)&wv[kk * 32 + g * 8 + 4];
                pk.u[0] = pack_bf2(f0.x, f0.y);
                pk.u[1] = pack_bf2(f0.z, f0.w);
                pk.u[2] = pack_bf2(f1.x, f1.y);
                pk.u[3] = pack_bf2(f1.z, f1.w);
            } else {
                pk.u[0] = pk.u[1] = pk.u[2] = pk.u[3] = 0u;
            }
            attb[kk] = pk.s;
        }
    }
    __syncthreads();

    for (int mt = blockIdx.x; mt < MACRO_TILES; mt += gridDim.x) {
        const int row0 = mt * 64;
#pragma unroll
        for (int i2 = 0; i2 < 4; i2++) {
            int row = rgrp + i2 * 16;
            int grow = row0 + row;
            u32x4 u4 = (grow < N_NODES)
                ? *(const u32x4*)&((const unsigned int*)Yin)[(size_t)grow * 64 + chunk * 4]
                : (u32x4){0u, 0u, 0u, 0u};
            u32x4 pk;
#pragma unroll
            for (int fq = 0; fq < 4; fq++) {
                unsigned int u = u4[fq];
                float v0 = bfbits2f(u & 0xFFFF) * sc[2*fq]   + sh[2*fq];   v0 = v0 > 0.f ? v0 : 0.01f * v0;
                float v1 = bfbits2f(u >> 16)    * sc[2*fq+1] + sh[2*fq+1]; v1 = v1 > 0.f ? v1 : 0.01f * v1;
                pk[fq] = pack_bf2(v0, v1);
            }
            *(u32x4*)&At[row * 136 + chunk * 8] = pk;
        }
        __syncthreads();
        f32x4 acc[NT];
#pragma unroll
        for (int c = 0; c < NT; c++) acc[c] = (f32x4){0.f, 0.f, 0.f, 0.f};
        f32x4 accA = (f32x4){0.f, 0.f, 0.f, 0.f};
#pragma unroll
        for (int kk = 0; kk < 4; kk++) {
            short8 af = *(const short8*)&At[(rg * 16 + m16) * 136 + kk * 32 + g * 8];
#pragma unroll
            for (int c = 0; c < NT; c++) {
                short8 bfr = *(const short8*)&Wt[(c * 16 + m16) * 136 + kk * 32 + g * 8];
                acc[c] = __builtin_amdgcn_mfma_f32_16x16x32_bf16(af, bfr, acc[c], 0, 0, 0);
            }
            if constexpr (ATT)
                accA = __builtin_amdgcn_mfma_f32_16x16x32_bf16(af, attb[kk], accA, 0, 0, 0);
        }
        const int orow = row0 + rg * 16 + g * 4;
#pragma unroll
        for (int c = 0; c < NT; c++) {
#pragma unroll
            for (int r = 0; r < 4; r++) {
                int grow = orow + r;
                if (grow < N_NODES)
                    hout[(size_t)grow * OSTRIDE + c * 16 + m16] = __float2bfloat16(acc[c][r]);
            }
        }
        if constexpr (ATT) {
            if (m16 < 2) {
                float* o = (m16 == 0) ? fs : fd;
#pragma unroll
                for (int r = 0; r < 4; r++) {
                    int grow = orow + r;
                    if (grow < N_NODES) o[grow] = accA[r];
                }
            }
        }
        __syncthreads();
    }
}

// ===== attention gather, 4-edges-per-wave dwordx4 + fused BN stats =====
// 1 node/wave; 4 groups of 16 lanes each load one 256B h-row (16B/lane);
// group-reduce via shfl_xor(16,32). XCD-aligned node mapping.
__global__ __launch_bounds__(256)
void k_gather_attn_bf(const int* __restrict__ cnt, const unsigned int* __restrict__ bucket,
                      const float* __restrict__ fs, const float* __restrict__ fd,
                      const bf16* __restrict__ h, bf16* __restrict__ y,
                      float* __restrict__ Psum, float* __restrict__ Psq) {
    const int xcd = blockIdx.x & 7;
    const int wb  = blockIdx.x >> 3;          // 0..399
    const int t = threadIdx.x;
    const int q = t >> 6;                     // wave 0..3
    const int lane = t & 63;
    const int grp = lane >> 4;                // edge group 0..3
    const int l = lane & 15;                  // 16B chunk id (8 feats)
    __shared__ int s_idx[4][CAP];
    __shared__ float s_e[4][CAP];
    __shared__ float sred[4][16][8];
    float ls[8], lq[8];
#pragma unroll
    for (int i = 0; i < 8; i++) { ls[i] = 0.f; lq[i] = 0.f; }

    for (int it = 0; it < ATT_IT; it++) {
        const int ni = (wb + it * 400) * 4 + q;       // wave-uniform
        if (ni >= NODE_RANGE) continue;               // no barriers inside
        const int d = xcd * NODE_RANGE + ni;
        const int deg = min(cnt[d], CAP);
        const float fdd = fd[d];
        if (lane < deg) {
            int s = bucket[d * CAP + lane] >> 15;
            float f = fs[s] + fdd;
            float lr = f > 0.f ? f : 0.2f * f;
            s_idx[q][lane] = s;
            s_e[q][lane] = __expf(-lr);
        }
        float a[8];
#pragma unroll
        for (int i = 0; i < 8; i++) a[i] = 0.f;
        float den = 0.f;
#pragma unroll 2
        for (int base = 0; base < deg; base += 4) {
            int k = base + grp;
            bool ev = k < deg;
            int kk = ev ? k : 0;
            float e = ev ? s_e[q][kk] : 0.f;
            int sidx = s_idx[q][kk];
            u32x4 u4 = *(const u32x4*)&((const unsigned int*)h)[(size_t)sidx * 64 + l * 4];
            den += e;
#pragma unroll
            for (int fq = 0; fq < 4; fq++) {
                unsigned int u = u4[fq];
                a[2*fq]   += e * bfbits2f(u & 0xFFFF);
                a[2*fq+1] += e * bfbits2f(u >> 16);
            }
        }
        // group reduce: xor 16, 32 (same-l lanes only)
#pragma unroll
        for (int off = 16; off < 64; off <<= 1) {
#pragma unroll
            for (int i = 0; i < 8; i++) a[i] += __shfl_xor(a[i], off);
            den += __shfl_xor(den, off);
        }
        float r = 1.f / (den + SEG_EPS);
        if (lane < 16) {
            u32x4 pk;
#pragma unroll
            for (int fq = 0; fq < 4; fq++) {
                float v0 = a[2*fq] * r, v1 = a[2*fq+1] * r;
                pk[fq] = pack_bf2(v0, v1);
                ls[2*fq] += v0;   lq[2*fq] += v0 * v0;
                ls[2*fq+1] += v1; lq[2*fq+1] += v1 * v1;
            }
            *(u32x4*)&((unsigned int*)y)[(size_t)d * 64 + l * 4] = pk;
        }
    }
    // block-wide stat partials
    if (lane < 16) {
#pragma unroll
        for (int i = 0; i < 8; i++) sred[q][l][i] = ls[i];
    }
    __syncthreads();
    if (t < 128) {
        int l16 = t >> 3, i8 = t & 7;
        Psum[blockIdx.x * 128 + t] =
            ((sred[0][l16][i8] + sred[1][l16][i8]) + sred[2][l16][i8]) + sred[3][l16][i8];
    }
    __syncthreads();
    if (lane < 16) {
#pragma unroll
        for (int i = 0; i < 8; i++) sred[q][l][i] = lq[i];
    }
    __syncthreads();
    if (t < 128) {
        int l16 = t >> 3, i8 = t & 7;
        Psq[blockIdx.x * 128 + t] =
            ((sred[0][l16][i8] + sred[1][l16][i8]) + sred[2][l16][i8]) + sred[3][l16][i8];
    }
}

// ===== final gather + epilogue, 4-edges-per-wave dwordx4 (sup stride 128) =====
__global__ __launch_bounds__(256)
void k_gather_out_bf(const int* __restrict__ cnt, const unsigned int* __restrict__ bucket,
                     const bf16* __restrict__ sup, const float* __restrict__ bg,
                     float* __restrict__ out) {
    const int xcd = blockIdx.x & 7;
    const int wb  = blockIdx.x >> 3;
    const int ni  = wb * 4 + (threadIdx.x >> 6);      // wave-uniform
    if (ni >= NODE_RANGE) return;
    const int d = xcd * NODE_RANGE + ni;
    const int t = threadIdx.x;
    const int q = t >> 6;
    const int lane = t & 63;
    const int grp = lane >> 4;
    const int l = lane & 15;
    __shared__ int s_idx[4][CAP];
    __shared__ float s_w[4][CAP];
    const int deg = min(cnt[d], CAP);
    if (lane < deg) {
        unsigned int b = bucket[d * CAP + lane];
        s_idx[q][lane] = b >> 15;
        s_w[q][lane] = (float)(b & 0x7FFF) * (1.f / (32767.f * 3.f));
    }
    float a[8];
#pragma unroll
    for (int i = 0; i < 8; i++) a[i] = 0.f;
#pragma unroll 2
    for (int base = 0; base < deg; base += 4) {
        int k = base + grp;
        bool ev = k < deg;
        int kk = ev ? k : 0;
        float w = ev ? s_w[q][kk] : 0.f;
        int sidx = s_idx[q][kk];
        u32x4 u4 = *(const u32x4*)&((const unsigned int*)sup)[(size_t)sidx * 64 + l * 4];
#pragma unroll
        for (int fq = 0; fq < 4; fq++) {
            unsigned int u = u4[fq];
            a[2*fq]   += w * bfbits2f(u & 0xFFFF);
            a[2*fq+1] += w * bfbits2f(u >> 16);
        }
    }
#pragma unroll
    for (int off = 16; off < 64; off <<= 1) {
#pragma unroll
        for (int i = 0; i < 8; i++) a[i] += __shfl_xor(a[i], off);
    }
    if (l < 14) {     // 14 chunks x 8 = 112 cols (chunks 14,15 are pad)
        u32x4 us = *(const u32x4*)&((const unsigned int*)sup)[(size_t)d * 64 + l * 4];
        const float4 b0 = *(const float4*)&bg[l * 8];
        const float4 b1 = *(const float4*)&bg[l * 8 + 4];
        float4 o0, o1;
        o0.x = a[0] + bfbits2f(us[0] & 0xFFFF) * (2.f/3.f) + b0.x;
        o0.y = a[1] + bfbits2f(us[0] >> 16)    * (2.f/3.f) + b0.y;
        o0.z = a[2] + bfbits2f(us[1] & 0xFFFF) * (2.f/3.f) + b0.z;
        o0.w = a[3] + bfbits2f(us[1] >> 16)    * (2.f/3.f) + b0.w;
        o1.x = a[4] + bfbits2f(us[2] & 0xFFFF) * (2.f/3.f) + b1.x;
        o1.y = a[5] + bfbits2f(us[2] >> 16)    * (2.f/3.f) + b1.y;
        o1.z = a[6] + bfbits2f(us[3] & 0xFFFF) * (2.f/3.f) + b1.z;
        o1.w = a[7] + bfbits2f(us[3] >> 16)    * (2.f/3.f) + b1.w;
        *(float4*)&out[(size_t)d * NCLASS + l * 8]     = o0;
        *(float4*)&out[(size_t)d * NCLASS + l * 8 + 4] = o1;
    }
}

extern "C" void kernel_launch(void* const* d_in, const int* in_sizes, int n_in,
                              void* d_out, int out_size, void* d_ws, size_t ws_size,
                              hipStream_t stream) {
    const float* x    = (const float*)d_in[0];
    const int*   ei   = (const int*)d_in[1];
    const float* ewt  = (const float*)d_in[2];
    const float* W1   = (const float*)d_in[3];
    const float* a1s  = (const float*)d_in[4];
    const float* a1d  = (const float*)d_in[5];
    const float* W2   = (const float*)d_in[6];
    const float* a2s  = (const float*)d_in[7];
    const float* a2d  = (const float*)d_in[8];
    const float* gam  = (const float*)d_in[9];
    const float* bet  = (const float*)d_in[10];
    const float* Wg   = (const float*)d_in[11];
    const float* bg   = (const float*)d_in[12];
    float* out = (float*)d_out;

    const int* src = ei;
    const int* dst = ei + N_EDGES;

    float* ws    = (float*)d_ws;
    bf16*  Yb    = (bf16*)ws;                       // [N,128] bf16 (y1, then y2)
    bf16*  Hb    = (bf16*)(ws + 3203072);           // [N,128] bf16 (h2 / support, stride 128)
    unsigned int* bucket = (unsigned int*)(ws + 6403072);   // [N*64] packed
    float* xagg  = ws + 9603072;                    // [N,8]
    float* fs    = ws + 10003072;                   // [N]
    float* fd    = ws + 10053072;                   // [N]
    int*   cnt   = (int*)(ws + 10103072);           // [N]
    float* scale = ws + 10153072;                   // [128]
    float* shift = scale + 128;                     // [128]
    float* w2s   = shift + 128;                     // [128]
    float* w2d   = w2s + 128;                       // [128]
    float* Psum  = ws + 10153600;                   // [3200][128]
    float* Psq   = Psum + 409600;                   // [3200][128]
    float* Qsum  = Psq + 409600;                    // [32][128]
    float* Qsq   = Qsum + 4096;                     // [32][128]

    // ---- bucketed CSR build (XCD-partitioned) + fused fsfd ----
    hipMemsetAsync(cnt, 0, (size_t)N_NODES * 4, stream);
    k_fill_fsfd<<<FILL_CHUNKS * 8 + FSFD_BLOCKS, 256, 0, stream>>>(
        src, dst, ewt, cnt, bucket, x, W1, a1s, a1d, fs, fd);

    // ---- layer 1 ----
    k_sort_gather_x<<<GATH_GRID, 256, 0, stream>>>(cnt, bucket, fs, fd, x, xagg);
    k_y1_gemm<<<Y1_BLOCKS, 256, 0, stream>>>(xagg, W1, Yb, Psum, Psq);
    k_bn_w2<<<33, 512, 0, stream>>>(Psum, Psq, gam, bet, scale, shift,
                                    W2, a2s, a2d, w2s, w2d);

    // ---- layer 2 ----
    k_gemm_mfma<128, 128, true><<<MACRO_TILES, 256, 0, stream>>>(Yb, scale, shift, W2, Hb,
                                                                 w2s, w2d, fs, fd);   // Hb = h2
    k_gather_attn_bf<<<ATT_GRID, 256, 0, stream>>>(cnt, bucket, fs, fd, Hb, Yb,
                                                   Psum, Psq);                        // Yb = y2 + stats
    k_reduce_a<<<16, 256, 0, stream>>>(Psum, Psq, ATT_GRID, 100, Qsum, Qsq);
    k_reduce_b<<<1, 512, 0, stream>>>(Qsum, Qsq, gam, bet, scale, shift);

    // ---- output head (support stored at stride 128 for aligned 16B gathers) ----
    k_gemm_mfma<112, 128, false><<<MACRO_TILES, 256, 0, stream>>>(Yb, scale, shift, Wg, Hb,
                                                                  nullptr, nullptr, nullptr, nullptr);
    k_gather_out_bf<<<GATH_GRID, 256, 0, stream>>>(cnt, bucket, Hb, bg, out);
}

// Round 4
// 299.214 us; speedup vs baseline: 1.1064x; 1.0687x over previous
//
#include <hip/hip_runtime.h>
#include <hip/hip_bf16.h>

#define N_NODES 50000
#define N_EDGES 800000
#define NFEAT   8
#define NHID    128
#define NCLASS  112
#define SEG_EPS 1e-16f
#define BN_EPS  1e-5f
#define CAP     64
#define MACRO_TILES 782   // ceil(50000/64)
#define NODE_RANGE 6250   // N_NODES / 8 (one dst-range per XCD)
#define FILL_CHUNK 2048   // edges per block (256 thr x 8)
#define FILL_CHUNKS 391   // ceil(800000 / 2048)
#define FSFD_BLOCKS 196   // ceil(50000/256)
#define GATH_GRID 12800   // 8 XCDs x 1600 blocks (4 node-slots each, 6400 >= 6250)
#define ATT_GRID 3200     // 8 XCDs x 400 blocks
#define ATT_IT 4          // 400*4 = 1600 quad-slots per range
#define Y1_BLOCKS 256     // y1 gemm grid == y1 stat partial count

typedef __hip_bfloat16 bf16;
typedef __attribute__((ext_vector_type(8))) short short8;
typedef __attribute__((ext_vector_type(4))) float f32x4;
typedef __attribute__((ext_vector_type(4))) unsigned int u32x4;

__device__ __forceinline__ float bfbits2f(unsigned int lo16) {
    union { unsigned int u; float f; } c; c.u = lo16 << 16; return c.f;
}

__device__ __forceinline__ unsigned int pack_bf2(float a, float b) {
    union { unsigned int u; bf16 h[2]; } t;
    t.h[0] = __float2bfloat16(a);
    t.h[1] = __float2bfloat16(b);
    return t.u;
}

// ============ bucketed CSR build (XCD-partitioned) + fused fsfd ============
__global__ __launch_bounds__(256)
void k_fill_fsfd(const int* __restrict__ src, const int* __restrict__ dst,
                 const float* __restrict__ ewt,
                 int* __restrict__ cnt, unsigned int* __restrict__ bucket,
                 const float* __restrict__ x, const float* __restrict__ W1,
                 const float* __restrict__ a1s, const float* __restrict__ a1d,
                 float* __restrict__ fs, float* __restrict__ fd) {
    if (blockIdx.x < FILL_CHUNKS * 8) {
        const int range = blockIdx.x & 7;
        const int chunk = blockIdx.x >> 3;
        const int lo = range * NODE_RANGE, hi = lo + NODE_RANGE;
        const int e0 = chunk * FILL_CHUNK + threadIdx.x * 8;
        if (e0 >= N_EDGES) return;        // 800000 % 8 == 0: all-or-nothing per thread
        const int4 d0 = *(const int4*)&dst[e0];
        const int4 d1 = *(const int4*)&dst[e0 + 4];
        const int dd[8] = {d0.x, d0.y, d0.z, d0.w, d1.x, d1.y, d1.z, d1.w};
#pragma unroll
        for (int i = 0; i < 8; i++) {
            int d = dd[i];
            if (d < lo || d >= hi) continue;
            int e = e0 + i;
            int slot = atomicAdd(&cnt[d], 1);
            if (slot < CAP) {
                unsigned int iw = (unsigned int)(ewt[e] * 32767.f + 0.5f);
                bucket[d * CAP + slot] = ((unsigned int)src[e] << 15) | iw;
            }
        }
        return;
    }
    // ---- fsfd part ----
    __shared__ float sw[16];              // [0..7] = w1s, [8..15] = w1d
    const int t = threadIdx.x, w = t >> 6, lane = t & 63;
#pragma unroll
    for (int dd = 0; dd < 4; dd++) {
        int dot = w + dd * 4;
        int k = dot & 7;
        const float* a = (dot < 8) ? a1s : a1d;
        float v = W1[k * NHID + lane] * a[lane] + W1[k * NHID + 64 + lane] * a[64 + lane];
#pragma unroll
        for (int off = 32; off > 0; off >>= 1) v += __shfl_down(v, off);
        if (lane == 0) sw[dot] = v;
    }
    __syncthreads();
    const int i = (blockIdx.x - FILL_CHUNKS * 8) * 256 + t;
    if (i < N_NODES) {
        const float4 x0 = ((const float4*)x)[i * 2];
        const float4 x1 = ((const float4*)x)[i * 2 + 1];
        fs[i] = x0.x*sw[0] + x0.y*sw[1] + x0.z*sw[2] + x0.w*sw[3]
              + x1.x*sw[4] + x1.y*sw[5] + x1.z*sw[6] + x1.w*sw[7];
        fd[i] = x0.x*sw[8] + x0.y*sw[9] + x0.z*sw[10] + x0.w*sw[11]
              + x1.x*sw[12] + x1.y*sw[13] + x1.z*sw[14] + x1.w*sw[15];
    }
}

// ===== canonical sort + layer-1 gather: XCD-aligned nodes, float4 gather =====
__global__ __launch_bounds__(256)
void k_sort_gather_x(const int* __restrict__ cnt, unsigned int* __restrict__ bucket,
                     const float* __restrict__ fs, const float* __restrict__ fd,
                     const float* __restrict__ x, float* __restrict__ xaggn) {
    const int xcd = blockIdx.x & 7;
    const int wb  = blockIdx.x >> 3;                  // 0..1599
    const int ni  = wb * 4 + (threadIdx.x >> 6);      // node-in-range (wave-uniform)
    if (ni >= NODE_RANGE) return;
    const int d = xcd * NODE_RANGE + ni;
    const int lane = threadIdx.x & 63;
    const int deg = min(cnt[d], CAP);
    unsigned int v = (lane < deg) ? bucket[d * CAP + lane] : 0xFFFFFFFFu;
#pragma unroll
    for (int k = 2; k <= 64; k <<= 1) {
#pragma unroll
        for (int s = k >> 1; s > 0; s >>= 1) {
            unsigned int o = (unsigned int)__shfl_xor((int)v, s);
            bool keepmin = ((lane & s) == 0) == ((lane & k) == 0);
            v = keepmin ? min(v, o) : max(v, o);
        }
    }
    if (lane < deg) bucket[d * CAP + lane] = v;
    // gather: 32 edge-slots x 2 feat-halves
    const int epair = lane >> 1;
    const int half  = lane & 1;
    const float fdd = fd[d];
    float4 acc = {0.f, 0.f, 0.f, 0.f};
    float den = 0.f;
    for (int base = 0; base < deg; base += 32) {
        int e = base + epair;                              // <= 63 always
        unsigned int u = (unsigned int)__shfl((int)v, e);  // sorted entry e
        if (e < deg) {
            int s = u >> 15;
            float f = fs[s] + fdd;
            float lr = f > 0.f ? f : 0.2f * f;
            float c = __expf(-lr);
            if (half == 0) den += c;
            const float4 xv = *(const float4*)&x[s * NFEAT + half * 4];
            acc.x += c * xv.x; acc.y += c * xv.y; acc.z += c * xv.z; acc.w += c * xv.w;
        }
    }
#pragma unroll
    for (int off = 2; off < 64; off <<= 1) {
        acc.x += __shfl_xor(acc.x, off);
        acc.y += __shfl_xor(acc.y, off);
        acc.z += __shfl_xor(acc.z, off);
        acc.w += __shfl_xor(acc.w, off);
        den   += __shfl_xor(den, off);
    }
    den += __shfl_xor(den, 1);   // odd lanes had 0
    if (lane < 2) {
        float r = 1.f / (den + SEG_EPS);
        float4 o;
        o.x = acc.x * r; o.y = acc.y * r; o.z = acc.z * r; o.w = acc.w * r;
        *(float4*)&xaggn[d * NFEAT + half * 4] = o;
    }
}

// y1(bf16) = xaggn @ W1; per-block stat partials (deterministic)
__global__ __launch_bounds__(256)
void k_y1_gemm(const float* __restrict__ xaggn, const float* __restrict__ W1,
               bf16* __restrict__ y1, float* __restrict__ Psum, float* __restrict__ Psq) {
    int t = threadIdx.x;
    int r = t >> 7, j = t & 127;
    float w[NFEAT];
#pragma unroll
    for (int k = 0; k < NFEAT; k++) w[k] = W1[k * NHID + j];
    float ls = 0.f, lq = 0.f;
    for (int row = blockIdx.x * 2 + r; row < N_NODES; row += gridDim.x * 2) {
        const float4 x0 = ((const float4*)xaggn)[row * 2];
        const float4 x1 = ((const float4*)xaggn)[row * 2 + 1];
        float v = x0.x*w[0] + x0.y*w[1] + x0.z*w[2] + x0.w*w[3]
                + x1.x*w[4] + x1.y*w[5] + x1.z*w[6] + x1.w*w[7];
        y1[(size_t)row * NHID + j] = __float2bfloat16(v);
        ls += v; lq += v * v;
    }
    __shared__ float sbuf[256];
    sbuf[t] = ls; __syncthreads();
    if (r == 0) Psum[blockIdx.x * 128 + j] = sbuf[j] + sbuf[j + 128];
    __syncthreads();
    sbuf[t] = lq; __syncthreads();
    if (r == 0) Psq[blockIdx.x * 128 + j] = sbuf[j] + sbuf[j + 128];
}

// block 0: full BN reduce (256 y1 partials); blocks 1..32: w2proj;
// blocks 33..48: W2 -> W2t bf16 transpose; blocks 49..62: Wg -> Wgt bf16 transpose
__global__ __launch_bounds__(512)
void k_bn_w2(const float* __restrict__ Psum, const float* __restrict__ Psq,
             const float* __restrict__ gamma, const float* __restrict__ beta,
             float* __restrict__ scale, float* __restrict__ shift,
             const float* __restrict__ W2,
             const float* __restrict__ as_, const float* __restrict__ ad_,
             float* __restrict__ ws_, float* __restrict__ wd_,
             const float* __restrict__ Wg,
             bf16* __restrict__ W2t, bf16* __restrict__ Wgt) {
    const int t = threadIdx.x;
    if (blockIdx.x == 0) {
        int j = t & 127;
        int g = t >> 7;
        float s = 0.f, q = 0.f;
#pragma unroll 8
        for (int b = g * 64; b < g * 64 + 64; b++) {
            s += Psum[b * 128 + j];
            q += Psq[b * 128 + j];
        }
        __shared__ float Ls[4][128], Lq[4][128];
        Ls[g][j] = s; Lq[g][j] = q;
        __syncthreads();
        if (g == 0) {
            float st = ((Ls[0][j] + Ls[1][j]) + Ls[2][j]) + Ls[3][j];
            float qt = ((Lq[0][j] + Lq[1][j]) + Lq[2][j]) + Lq[3][j];
            float mu = st * (1.f / N_NODES);
            float var = qt * (1.f / N_NODES) - mu * mu;
            float rs = rsqrtf(var + BN_EPS);
            float ga = gamma[j];
            scale[j] = rs * ga;
            shift[j] = beta[j] - mu * rs * ga;
        }
        return;
    }
    if (blockIdx.x < 33) {
        // w2proj: k = (b-1)*4 + (t>>7), n = t&127
        const int k = (blockIdx.x - 1) * 4 + (t >> 7);
        const int n = t & 127;
        float wv = W2[k * NHID + n];
        float vs = wv * as_[n], vd = wv * ad_[n];
#pragma unroll
        for (int off = 32; off > 0; off >>= 1) { vs += __shfl_down(vs, off); vd += __shfl_down(vd, off); }
        __shared__ float ps[8], pd[8];
        const int wid = t >> 6;
        if ((t & 63) == 0) { ps[wid] = vs; pd[wid] = vd; }
        __syncthreads();
        if ((t & 127) == 0) { ws_[k] = ps[wid] + ps[wid + 1]; wd_[k] = pd[wid] + pd[wid + 1]; }
        return;
    }
    if (blockIdx.x < 49) {
        // W2t[n][k] = bf16(W2[k][n]); 8 n-rows per block
        const int n = (blockIdx.x - 33) * 8 + (t >> 6);
        const int k2 = (t & 63) * 2;
        float v0 = W2[k2 * NHID + n];
        float v1 = W2[(k2 + 1) * NHID + n];
        *(unsigned int*)&W2t[n * 128 + k2] = pack_bf2(v0, v1);
        return;
    }
    // Wgt[n][k] = bf16(Wg[k][n]); n < 112; 8 n-rows per block
    const int n = (blockIdx.x - 49) * 8 + (t >> 6);
    const int k2 = (t & 63) * 2;
    float v0 = Wg[k2 * NCLASS + n];
    float v1 = Wg[(k2 + 1) * NCLASS + n];
    *(unsigned int*)&Wgt[n * 128 + k2] = pack_bf2(v0, v1);
}

// ---- deterministic two-stage partial reduction (y2 path) ----
__global__ __launch_bounds__(256)
void k_reduce_a(const float* __restrict__ Psum, const float* __restrict__ Psq,
                int nIn, int chunk,
                float* __restrict__ Qsum, float* __restrict__ Qsq) {
    int j = threadIdx.x & 127;
    int h = threadIdx.x >> 7;
    int u = blockIdx.x * 2 + h;
    int b0 = u * chunk, b1 = min(b0 + chunk, nIn);
    float s = 0.f, q = 0.f;
#pragma unroll 8
    for (int b = b0; b < b1; b++) {
        s += Psum[b * 128 + j];
        q += Psq[b * 128 + j];
    }
    Qsum[u * 128 + j] = s;
    Qsq[u * 128 + j] = q;
}

__global__ __launch_bounds__(512)
void k_reduce_b(const float* __restrict__ Qsum, const float* __restrict__ Qsq,
                const float* __restrict__ gamma, const float* __restrict__ beta,
                float* __restrict__ scale, float* __restrict__ shift) {
    int j = threadIdx.x & 127;
    int g = threadIdx.x >> 7;
    float s = 0.f, q = 0.f;
#pragma unroll
    for (int u = g * 8; u < g * 8 + 8; u++) {
        s += Qsum[u * 128 + j];
        q += Qsq[u * 128 + j];
    }
    __shared__ float Ls[4][128], Lq[4][128];
    Ls[g][j] = s; Lq[g][j] = q;
    __syncthreads();
    if (g == 0) {
        float st = ((Ls[0][j] + Ls[1][j]) + Ls[2][j]) + Ls[3][j];
        float qt = ((Lq[0][j] + Lq[1][j]) + Lq[2][j]) + Lq[3][j];
        float mu = st * (1.f / N_NODES);
        float var = qt * (1.f / N_NODES) - mu * mu;
        float rs = rsqrtf(var + BN_EPS);
        float ga = gamma[j];
        scale[j] = rs * ga;
        shift[j] = beta[j] - mu * rs * ga;
    }
}

// ===== MFMA GEMM v2: direct-A from global, prestaged bf16 B =====
// hout[N,128](bf16) = lrelu(bn(Yin[N,128])) @ Wt_g^T  (Wt_g is [NCV][128] bf16)
// No At LDS: each lane loads its 16B A-chunk, applies BN+lrelu in regs, packs.
// One tile per block (grid == MACRO_TILES), single prologue barrier.
template<int NCV, bool ATT>
__global__ __launch_bounds__(256)
void k_gemm_mfma(const bf16* __restrict__ Yin,
                 const float* __restrict__ scale, const float* __restrict__ shift,
                 const bf16* __restrict__ Wt_g,
                 bf16* __restrict__ hout,
                 const float* __restrict__ w2s, const float* __restrict__ w2d,
                 float* __restrict__ fs, float* __restrict__ fd) {
    constexpr int NT = NCV / 16;
    __shared__ bf16 Wt[NCV * 136];   // [n][k], pad 136 -> 2-way (free) on frag reads
    __shared__ float scb[128], shb[128];
    const int t = threadIdx.x;
    // FIXED staging: 16 x 8-bf16 (16B) chunks per 128-bf16 row, fully contiguous
    for (int idx = t; idx < NCV * 16; idx += 256) {
        int n = idx >> 4, c = idx & 15;
        *(u32x4*)&Wt[n * 136 + c * 8] = *(const u32x4*)&Wt_g[n * 128 + c * 8];
    }
    if (t < 128) { scb[t] = scale[t]; shb[t] = shift[t]; }
    const int lane = t & 63;
    const int m16 = lane & 15;
    const int g = lane >> 4;        // k-chunk / output quad
    const int rg = t >> 6;          // wave id
    short8 attb[4];
    if constexpr (ATT) {
#pragma unroll
        for (int kk = 0; kk < 4; kk++) {
            union { short8 s; unsigned int u[4]; } pk;
            if (m16 < 2) {
                const float* wv = (m16 == 0) ? w2s : w2d;
                const float4 f0 = *(const float4*)&wv[kk * 32 + g * 8];
                const float4 f1 = *(const float4*)&wv[kk * 32 + g * 8 + 4];
                pk.u[0] = pack_bf2(f0.x, f0.y);
                pk.u[1] = pack_bf2(f0.z, f0.w);
                pk.u[2] = pack_bf2(f1.x, f1.y);
                pk.u[3] = pack_bf2(f1.z, f1.w);
            } else {
                pk.u[0] = pk.u[1] = pk.u[2] = pk.u[3] = 0u;
            }
            attb[kk] = pk.s;
        }
    }
    __syncthreads();

    const int row0 = blockIdx.x * 64;
    const int arow = row0 + rg * 16 + m16;
    const bool rok = arow < N_NODES;
    f32x4 acc[NT];
#pragma unroll
    for (int c = 0; c < NT; c++) acc[c] = (f32x4){0.f, 0.f, 0.f, 0.f};
    f32x4 accA = (f32x4){0.f, 0.f, 0.f, 0.f};
#pragma unroll
    for (int kk = 0; kk < 4; kk++) {
        u32x4 u4 = rok
            ? *(const u32x4*)&((const unsigned int*)Yin)[(size_t)arow * 64 + kk * 16 + g * 4]
            : (u32x4){0u, 0u, 0u, 0u};
        const float4 s0 = *(const float4*)&scb[kk * 32 + g * 8];
        const float4 s1 = *(const float4*)&scb[kk * 32 + g * 8 + 4];
        const float4 h0 = *(const float4*)&shb[kk * 32 + g * 8];
        const float4 h1 = *(const float4*)&shb[kk * 32 + g * 8 + 4];
        const float scv[8] = {s0.x, s0.y, s0.z, s0.w, s1.x, s1.y, s1.z, s1.w};
        const float shv[8] = {h0.x, h0.y, h0.z, h0.w, h1.x, h1.y, h1.z, h1.w};
        union { short8 s; unsigned int u[4]; } A;
#pragma unroll
        for (int fq = 0; fq < 4; fq++) {
            unsigned int u = u4[fq];
            float v0 = bfbits2f(u & 0xFFFF) * scv[2*fq]   + shv[2*fq];   v0 = v0 > 0.f ? v0 : 0.01f * v0;
            float v1 = bfbits2f(u >> 16)    * scv[2*fq+1] + shv[2*fq+1]; v1 = v1 > 0.f ? v1 : 0.01f * v1;
            A.u[fq] = pack_bf2(v0, v1);
        }
#pragma unroll
        for (int c = 0; c < NT; c++) {
            short8 bfr = *(const short8*)&Wt[(c * 16 + m16) * 136 + kk * 32 + g * 8];
            acc[c] = __builtin_amdgcn_mfma_f32_16x16x32_bf16(A.s, bfr, acc[c], 0, 0, 0);
        }
        if constexpr (ATT)
            accA = __builtin_amdgcn_mfma_f32_16x16x32_bf16(A.s, attb[kk], accA, 0, 0, 0);
    }
    const int orow = row0 + rg * 16 + g * 4;
#pragma unroll
    for (int c = 0; c < NT; c++) {
#pragma unroll
        for (int r = 0; r < 4; r++) {
            int grow = orow + r;
            if (grow < N_NODES)
                hout[(size_t)grow * 128 + c * 16 + m16] = __float2bfloat16(acc[c][r]);
        }
    }
    if constexpr (ATT) {
        if (m16 < 2) {
            float* o = (m16 == 0) ? fs : fd;
#pragma unroll
            for (int r = 0; r < 4; r++) {
                int grow = orow + r;
                if (grow < N_NODES) o[grow] = accA[r];
            }
        }
    }
}

// ===== attention gather, 4-edges-per-wave dwordx4 + fused BN stats =====
__global__ __launch_bounds__(256)
void k_gather_attn_bf(const int* __restrict__ cnt, const unsigned int* __restrict__ bucket,
                      const float* __restrict__ fs, const float* __restrict__ fd,
                      const bf16* __restrict__ h, bf16* __restrict__ y,
                      float* __restrict__ Psum, float* __restrict__ Psq) {
    const int xcd = blockIdx.x & 7;
    const int wb  = blockIdx.x >> 3;          // 0..399
    const int t = threadIdx.x;
    const int q = t >> 6;                     // wave 0..3
    const int lane = t & 63;
    const int grp = lane >> 4;                // edge group 0..3
    const int l = lane & 15;                  // 16B chunk id (8 feats)
    __shared__ int s_idx[4][CAP];
    __shared__ float s_e[4][CAP];
    __shared__ float sred[4][16][8];
    float ls[8], lq[8];
#pragma unroll
    for (int i = 0; i < 8; i++) { ls[i] = 0.f; lq[i] = 0.f; }

    for (int it = 0; it < ATT_IT; it++) {
        const int ni = (wb + it * 400) * 4 + q;       // wave-uniform
        if (ni >= NODE_RANGE) continue;               // no barriers inside
        const int d = xcd * NODE_RANGE + ni;
        const int deg = min(cnt[d], CAP);
        const float fdd = fd[d];
        if (lane < deg) {
            int s = bucket[d * CAP + lane] >> 15;
            float f = fs[s] + fdd;
            float lr = f > 0.f ? f : 0.2f * f;
            s_idx[q][lane] = s;
            s_e[q][lane] = __expf(-lr);
        }
        float a[8];
#pragma unroll
        for (int i = 0; i < 8; i++) a[i] = 0.f;
        float den = 0.f;
#pragma unroll 4
        for (int base = 0; base < deg; base += 4) {
            int k = base + grp;
            bool ev = k < deg;
            int kk = ev ? k : 0;
            float e = ev ? s_e[q][kk] : 0.f;
            int sidx = s_idx[q][kk];
            u32x4 u4 = *(const u32x4*)&((const unsigned int*)h)[(size_t)sidx * 64 + l * 4];
            den += e;
#pragma unroll
            for (int fq = 0; fq < 4; fq++) {
                unsigned int u = u4[fq];
                a[2*fq]   += e * bfbits2f(u & 0xFFFF);
                a[2*fq+1] += e * bfbits2f(u >> 16);
            }
        }
        // group reduce: xor 16, 32 (same-l lanes only)
#pragma unroll
        for (int off = 16; off < 64; off <<= 1) {
#pragma unroll
            for (int i = 0; i < 8; i++) a[i] += __shfl_xor(a[i], off);
            den += __shfl_xor(den, off);
        }
        float r = 1.f / (den + SEG_EPS);
        if (lane < 16) {
            u32x4 pk;
#pragma unroll
            for (int fq = 0; fq < 4; fq++) {
                float v0 = a[2*fq] * r, v1 = a[2*fq+1] * r;
                pk[fq] = pack_bf2(v0, v1);
                ls[2*fq] += v0;   lq[2*fq] += v0 * v0;
                ls[2*fq+1] += v1; lq[2*fq+1] += v1 * v1;
            }
            *(u32x4*)&((unsigned int*)y)[(size_t)d * 64 + l * 4] = pk;
        }
    }
    // block-wide stat partials
    if (lane < 16) {
#pragma unroll
        for (int i = 0; i < 8; i++) sred[q][l][i] = ls[i];
    }
    __syncthreads();
    if (t < 128) {
        int l16 = t >> 3, i8 = t & 7;
        Psum[blockIdx.x * 128 + t] =
            ((sred[0][l16][i8] + sred[1][l16][i8]) + sred[2][l16][i8]) + sred[3][l16][i8];
    }
    __syncthreads();
    if (lane < 16) {
#pragma unroll
        for (int i = 0; i < 8; i++) sred[q][l][i] = lq[i];
    }
    __syncthreads();
    if (t < 128) {
        int l16 = t >> 3, i8 = t & 7;
        Psq[blockIdx.x * 128 + t] =
            ((sred[0][l16][i8] + sred[1][l16][i8]) + sred[2][l16][i8]) + sred[3][l16][i8];
    }
}

// ===== final gather + epilogue, 4-edges-per-wave dwordx4 (sup stride 128) =====
__global__ __launch_bounds__(256)
void k_gather_out_bf(const int* __restrict__ cnt, const unsigned int* __restrict__ bucket,
                     const bf16* __restrict__ sup, const float* __restrict__ bg,
                     float* __restrict__ out) {
    const int xcd = blockIdx.x & 7;
    const int wb  = blockIdx.x >> 3;
    const int ni  = wb * 4 + (threadIdx.x >> 6);      // wave-uniform
    if (ni >= NODE_RANGE) return;
    const int d = xcd * NODE_RANGE + ni;
    const int t = threadIdx.x;
    const int q = t >> 6;
    const int lane = t & 63;
    const int grp = lane >> 4;
    const int l = lane & 15;
    __shared__ int s_idx[4][CAP];
    __shared__ float s_w[4][CAP];
    const int deg = min(cnt[d], CAP);
    if (lane < deg) {
        unsigned int b = bucket[d * CAP + lane];
        s_idx[q][lane] = b >> 15;
        s_w[q][lane] = (float)(b & 0x7FFF) * (1.f / (32767.f * 3.f));
    }
    float a[8];
#pragma unroll
    for (int i = 0; i < 8; i++) a[i] = 0.f;
#pragma unroll 4
    for (int base = 0; base < deg; base += 4) {
        int k = base + grp;
        bool ev = k < deg;
        int kk = ev ? k : 0;
        float w = ev ? s_w[q][kk] : 0.f;
        int sidx = s_idx[q][kk];
        u32x4 u4 = *(const u32x4*)&((const unsigned int*)sup)[(size_t)sidx * 64 + l * 4];
#pragma unroll
        for (int fq = 0; fq < 4; fq++) {
            unsigned int u = u4[fq];
            a[2*fq]   += w * bfbits2f(u & 0xFFFF);
            a[2*fq+1] += w * bfbits2f(u >> 16);
        }
    }
#pragma unroll
    for (int off = 16; off < 64; off <<= 1) {
#pragma unroll
        for (int i = 0; i < 8; i++) a[i] += __shfl_xor(a[i], off);
    }
    if (l < 14) {     // 14 chunks x 8 = 112 cols (chunks 14,15 are pad)
        u32x4 us = *(const u32x4*)&((const unsigned int*)sup)[(size_t)d * 64 + l * 4];
        const float4 b0 = *(const float4*)&bg[l * 8];
        const float4 b1 = *(const float4*)&bg[l * 8 + 4];
        float4 o0, o1;
        o0.x = a[0] + bfbits2f(us[0] & 0xFFFF) * (2.f/3.f) + b0.x;
        o0.y = a[1] + bfbits2f(us[0] >> 16)    * (2.f/3.f) + b0.y;
        o0.z = a[2] + bfbits2f(us[1] & 0xFFFF) * (2.f/3.f) + b0.z;
        o0.w = a[3] + bfbits2f(us[1] >> 16)    * (2.f/3.f) + b0.w;
        o1.x = a[4] + bfbits2f(us[2] & 0xFFFF) * (2.f/3.f) + b1.x;
        o1.y = a[5] + bfbits2f(us[2] >> 16)    * (2.f/3.f) + b1.y;
        o1.z = a[6] + bfbits2f(us[3] & 0xFFFF) * (2.f/3.f) + b1.z;
        o1.w = a[7] + bfbits2f(us[3] >> 16)    * (2.f/3.f) + b1.w;
        *(float4*)&out[(size_t)d * NCLASS + l * 8]     = o0;
        *(float4*)&out[(size_t)d * NCLASS + l * 8 + 4] = o1;
    }
}

extern "C" void kernel_launch(void* const* d_in, const int* in_sizes, int n_in,
                              void* d_out, int out_size, void* d_ws, size_t ws_size,
                              hipStream_t stream) {
    const float* x    = (const float*)d_in[0];
    const int*   ei   = (const int*)d_in[1];
    const float* ewt  = (const float*)d_in[2];
    const float* W1   = (const float*)d_in[3];
    const float* a1s  = (const float*)d_in[4];
    const float* a1d  = (const float*)d_in[5];
    const float* W2   = (const float*)d_in[6];
    const float* a2s  = (const float*)d_in[7];
    const float* a2d  = (const float*)d_in[8];
    const float* gam  = (const float*)d_in[9];
    const float* bet  = (const float*)d_in[10];
    const float* Wg   = (const float*)d_in[11];
    const float* bg   = (const float*)d_in[12];
    float* out = (float*)d_out;

    const int* src = ei;
    const int* dst = ei + N_EDGES;

    float* ws    = (float*)d_ws;
    bf16*  Yb    = (bf16*)ws;                       // [N,128] bf16 (y1, then y2)
    bf16*  Hb    = (bf16*)(ws + 3203072);           // [N,128] bf16 (h2 / support, stride 128)
    unsigned int* bucket = (unsigned int*)(ws + 6403072);   // [N*64] packed
    float* xagg  = ws + 9603072;                    // [N,8]
    float* fs    = ws + 10003072;                   // [N]
    float* fd    = ws + 10053072;                   // [N]
    int*   cnt   = (int*)(ws + 10103072);           // [N]
    float* scale = ws + 10153072;                   // [128]
    float* shift = scale + 128;                     // [128]
    float* w2s   = shift + 128;                     // [128]
    float* w2d   = w2s + 128;                       // [128]
    float* Psum  = ws + 10153600;                   // [3200][128]
    float* Psq   = Psum + 409600;                   // [3200][128]
    float* Qsum  = Psq + 409600;                    // [32][128]
    float* Qsq   = Qsum + 4096;                     // [32][128]
    bf16*  W2t   = (bf16*)(ws + 10980992);          // [128][128] bf16 (8192 floats)
    bf16*  Wgt   = W2t + 16384;                     // [112][128] bf16 (7168 floats)
                                                    // ends at float 10996352 (< prior HWM)

    // ---- bucketed CSR build (XCD-partitioned) + fused fsfd ----
    hipMemsetAsync(cnt, 0, (size_t)N_NODES * 4, stream);
    k_fill_fsfd<<<FILL_CHUNKS * 8 + FSFD_BLOCKS, 256, 0, stream>>>(
        src, dst, ewt, cnt, bucket, x, W1, a1s, a1d, fs, fd);

    // ---- layer 1 ----
    k_sort_gather_x<<<GATH_GRID, 256, 0, stream>>>(cnt, bucket, fs, fd, x, xagg);
    k_y1_gemm<<<Y1_BLOCKS, 256, 0, stream>>>(xagg, W1, Yb, Psum, Psq);
    k_bn_w2<<<63, 512, 0, stream>>>(Psum, Psq, gam, bet, scale, shift,
                                    W2, a2s, a2d, w2s, w2d, Wg, W2t, Wgt);

    // ---- layer 2 ----
    k_gemm_mfma<128, true><<<MACRO_TILES, 256, 0, stream>>>(Yb, scale, shift, W2t, Hb,
                                                            w2s, w2d, fs, fd);    // Hb = h2
    k_gather_attn_bf<<<ATT_GRID, 256, 0, stream>>>(cnt, bucket, fs, fd, Hb, Yb,
                                                   Psum, Psq);                    // Yb = y2 + stats
    k_reduce_a<<<16, 256, 0, stream>>>(Psum, Psq, ATT_GRID, 100, Qsum, Qsq);
    k_reduce_b<<<1, 512, 0, stream>>>(Qsum, Qsq, gam, bet, scale, shift);

    // ---- output head (support stored at stride 128 for aligned 16B gathers) ----
    k_gemm_mfma<112, false><<<MACRO_TILES, 256, 0, stream>>>(Yb, scale, shift, Wgt, Hb,
                                                             nullptr, nullptr, nullptr, nullptr);
    k_gather_out_bf<<<GATH_GRID, 256, 0, stream>>>(cnt, bucket, Hb, bg, out);
}

// Round 7
// 295.819 us; speedup vs baseline: 1.1191x; 1.0115x over previous
//
#include <hip/hip_runtime.h>
#include <hip/hip_bf16.h>

#define N_NODES 50000
#define N_EDGES 800000
#define NFEAT   8
#define NHID    128
#define NCLASS  112
#define SEG_EPS 1e-16f
#define BN_EPS  1e-5f
#define CAP     64
#define MACRO_TILES 782   // ceil(50000/64)
#define NODE_RANGE 6250   // N_NODES / 8 (one dst-range per XCD)
#define FILL_CHUNK 2048   // edges per block (256 thr x 8)
#define FILL_CHUNKS 391   // ceil(800000 / 2048)
#define FSFD_BLOCKS 196   // ceil(50000/256)
#define GATH_GRID 12800   // 8 XCDs x 1600 blocks (4 node-slots each, 6400 >= 6250)
#define ATT_GRID 3200     // 8 XCDs x 400 blocks
#define ATT_IT 4          // 400*4 = 1600 quad-slots per range

// block roles in k_fill_fsfd
#define FILLB (FILL_CHUNKS * 8)        // 3128
#define FSFD0 FILLB                    // 3128
#define W2P0  (FSFD0 + FSFD_BLOCKS)    // 3324  (64 blocks: w2proj, 2 k-rows each)
#define W2T0  (W2P0 + 64)              // 3388  (32 blocks: W2t transpose, 4 rows each)
#define WGT0  (W2T0 + 32)              // 3420  (28 blocks: Wgt transpose, 4 rows each)
#define GRID_FILL (WGT0 + 28)          // 3448

typedef __hip_bfloat16 bf16;
typedef __attribute__((ext_vector_type(8))) short short8;
typedef __attribute__((ext_vector_type(4))) float f32x4;
typedef __attribute__((ext_vector_type(4))) unsigned int u32x4;
typedef __attribute__((ext_vector_type(4))) int i32x4;

__device__ __forceinline__ float bfbits2f(unsigned int lo16) {
    union { unsigned int u; float f; } c; c.u = lo16 << 16; return c.f;
}

__device__ __forceinline__ unsigned int pack_bf2(float a, float b) {
    union { unsigned int u; bf16 h[2]; } t;
    t.h[0] = __float2bfloat16(a);
    t.h[1] = __float2bfloat16(b);
    return t.u;
}

// ======= bucketed CSR build (XCD-partitioned, nt streaming loads) =======
// + fused: fsfd projections, w2proj, W2t/Wgt bf16 transposes (input-only deps).
// nt loads keep the streaming edge data OUT of L2 so each XCD's 1.6MB bucket
// slice + cnt stay resident (fixes the eviction-writeback thrash seen in
// rocprof: WRITE_SIZE 38.6MB for a 3.2MB logical write).
__global__ __launch_bounds__(256)
void k_fill_fsfd(const int* __restrict__ src, const int* __restrict__ dst,
                 const float* __restrict__ ewt,
                 int* __restrict__ cnt, unsigned int* __restrict__ bucket,
                 const float* __restrict__ x, const float* __restrict__ W1,
                 const float* __restrict__ a1s, const float* __restrict__ a1d,
                 float* __restrict__ fs, float* __restrict__ fd,
                 const float* __restrict__ W2,
                 const float* __restrict__ a2s, const float* __restrict__ a2d,
                 float* __restrict__ w2s, float* __restrict__ w2d,
                 const float* __restrict__ Wg,
                 bf16* __restrict__ W2t, bf16* __restrict__ Wgt) {
    __shared__ float sw[16];
    __shared__ float ps[4], pd[4];
    const int t = threadIdx.x;
    if (blockIdx.x < FILLB) {
        const int range = blockIdx.x & 7;
        const int chunk = blockIdx.x >> 3;
        const int lo = range * NODE_RANGE, hi = lo + NODE_RANGE;
        const int e0 = chunk * FILL_CHUNK + t * 8;
        if (e0 >= N_EDGES) return;        // 800000 % 8 == 0: all-or-nothing per thread
        const i32x4 d0 = __builtin_nontemporal_load((const i32x4*)&dst[e0]);
        const i32x4 d1 = __builtin_nontemporal_load((const i32x4*)&dst[e0 + 4]);
        const int dd[8] = {d0.x, d0.y, d0.z, d0.w, d1.x, d1.y, d1.z, d1.w};
#pragma unroll
        for (int i = 0; i < 8; i++) {
            int d = dd[i];
            if (d < lo || d >= hi) continue;
            int e = e0 + i;
            int slot = atomicAdd(&cnt[d], 1);
            if (slot < CAP) {
                float w = __builtin_nontemporal_load(&ewt[e]);
                int   s = __builtin_nontemporal_load(&src[e]);
                unsigned int iw = (unsigned int)(w * 32767.f + 0.5f);
                bucket[d * CAP + slot] = ((unsigned int)s << 15) | iw;
            }
        }
        return;
    }
    if (blockIdx.x < W2P0) {
        // ---- fsfd ----
        const int w = t >> 6, lane = t & 63;
#pragma unroll
        for (int dd = 0; dd < 4; dd++) {
            int dot = w + dd * 4;
            int k = dot & 7;
            const float* a = (dot < 8) ? a1s : a1d;
            float v = W1[k * NHID + lane] * a[lane] + W1[k * NHID + 64 + lane] * a[64 + lane];
#pragma unroll
            for (int off = 32; off > 0; off >>= 1) v += __shfl_down(v, off);
            if (lane == 0) sw[dot] = v;
        }
        __syncthreads();
        const int i = (blockIdx.x - FSFD0) * 256 + t;
        if (i < N_NODES) {
            const float4 x0 = ((const float4*)x)[i * 2];
            const float4 x1 = ((const float4*)x)[i * 2 + 1];
            fs[i] = x0.x*sw[0] + x0.y*sw[1] + x0.z*sw[2] + x0.w*sw[3]
                  + x1.x*sw[4] + x1.y*sw[5] + x1.z*sw[6] + x1.w*sw[7];
            fd[i] = x0.x*sw[8] + x0.y*sw[9] + x0.z*sw[10] + x0.w*sw[11]
                  + x1.x*sw[12] + x1.y*sw[13] + x1.z*sw[14] + x1.w*sw[15];
        }
        return;
    }
    if (blockIdx.x < W2T0) {
        // ---- w2proj: 2 k-rows per block ----
        const int k = (blockIdx.x - W2P0) * 2 + (t >> 7);
        const int n = t & 127;
        float wv = W2[k * NHID + n];
        float vs = wv * a2s[n], vd = wv * a2d[n];
#pragma unroll
        for (int off = 32; off > 0; off >>= 1) { vs += __shfl_down(vs, off); vd += __shfl_down(vd, off); }
        const int wid = t >> 6;
        if ((t & 63) == 0) { ps[wid] = vs; pd[wid] = vd; }
        __syncthreads();
        if ((t & 127) == 0) { w2s[k] = ps[wid] + ps[wid + 1]; w2d[k] = pd[wid] + pd[wid + 1]; }
        return;
    }
    if (blockIdx.x < WGT0) {
        // ---- W2t[n][k] = bf16(W2[k][n]); 4 rows per block ----
        const int n = (blockIdx.x - W2T0) * 4 + (t >> 6);
        const int k2 = (t & 63) * 2;
        *(unsigned int*)&W2t[n * 128 + k2] = pack_bf2(W2[k2 * NHID + n], W2[(k2 + 1) * NHID + n]);
        return;
    }
    // ---- Wgt[n][k] = bf16(Wg[k][n]); n < 112; 4 rows per block ----
    const int n = (blockIdx.x - WGT0) * 4 + (t >> 6);
    const int k2 = (t & 63) * 2;
    *(unsigned int*)&Wgt[n * 128 + k2] = pack_bf2(Wg[k2 * NCLASS + n], Wg[(k2 + 1) * NCLASS + n]);
}

// ===== sort + layer-1 gather + y1 projection + BN stat partials, fused =====
// After the butterfly reduce every lane holds half of xagg; one shfl_xor(1)
// broadcasts all 8 features, then each lane computes y1 cols (2j, 2j+1)
// directly (16 FMA) -> no xagg buffer, no separate y1 GEMM pass.
__global__ __launch_bounds__(256)
void k_sort_gather_y1(const int* __restrict__ cnt, unsigned int* __restrict__ bucket,
                      const float* __restrict__ fs, const float* __restrict__ fd,
                      const float* __restrict__ x, const float* __restrict__ W1,
                      bf16* __restrict__ y1,
                      float* __restrict__ Psum, float* __restrict__ Psq) {
    const int xcd = blockIdx.x & 7;
    const int wb  = blockIdx.x >> 3;                  // 0..1599
    const int t = threadIdx.x;
    const int q = t >> 6;                             // wave 0..3 (one node each)
    const int lane = t & 63;
    const int ni = wb * 4 + q;
    const bool nok = ni < NODE_RANGE;
    const int d = xcd * NODE_RANGE + ni;              // only dereferenced if nok
    // per-lane W1 columns 2*lane, 2*lane+1 (block-invariant)
    float w1c0[8], w1c1[8];
#pragma unroll
    for (int k = 0; k < 8; k++) {
        const float2 wv = *(const float2*)&W1[k * NHID + 2 * lane];
        w1c0[k] = wv.x; w1c1[k] = wv.y;
    }
    float v0 = 0.f, v1 = 0.f;
    if (nok) {
        const int deg = min(cnt[d], CAP);
        unsigned int v = (lane < deg) ? bucket[d * CAP + lane] : 0xFFFFFFFFu;
#pragma unroll
        for (int k = 2; k <= 64; k <<= 1) {
#pragma unroll
            for (int s = k >> 1; s > 0; s >>= 1) {
                unsigned int o = (unsigned int)__shfl_xor((int)v, s);
                bool keepmin = ((lane & s) == 0) == ((lane & k) == 0);
                v = keepmin ? min(v, o) : max(v, o);
            }
        }
        if (lane < deg) bucket[d * CAP + lane] = v;
        // gather: 32 edge-slots x 2 feat-halves
        const int epair = lane >> 1;
        const int half  = lane & 1;
        const float fdd = fd[d];
        float4 acc = {0.f, 0.f, 0.f, 0.f};
        float den = 0.f;
        for (int base = 0; base < deg; base += 32) {
            int e = base + epair;                              // <= 63 always
            unsigned int u = (unsigned int)__shfl((int)v, e);  // sorted entry e
            if (e < deg) {
                int s = u >> 15;
                float f = fs[s] + fdd;
                float lr = f > 0.f ? f : 0.2f * f;
                float c = __expf(-lr);
                if (half == 0) den += c;
                const float4 xv = *(const float4*)&x[s * NFEAT + half * 4];
                acc.x += c * xv.x; acc.y += c * xv.y; acc.z += c * xv.z; acc.w += c * xv.w;
            }
        }
#pragma unroll
        for (int off = 2; off < 64; off <<= 1) {
            acc.x += __shfl_xor(acc.x, off);
            acc.y += __shfl_xor(acc.y, off);
            acc.z += __shfl_xor(acc.z, off);
            acc.w += __shfl_xor(acc.w, off);
            den   += __shfl_xor(den, off);
        }
        den += __shfl_xor(den, 1);   // odd lanes had 0
        // broadcast the other half of xagg
        float4 oth;
        oth.x = __shfl_xor(acc.x, 1);
        oth.y = __shfl_xor(acc.y, 1);
        oth.z = __shfl_xor(acc.z, 1);
        oth.w = __shfl_xor(acc.w, 1);
        const float r = 1.f / (den + SEG_EPS);
        float xa[8];
        if ((lane & 1) == 0) {
            xa[0]=acc.x*r; xa[1]=acc.y*r; xa[2]=acc.z*r; xa[3]=acc.w*r;
            xa[4]=oth.x*r; xa[5]=oth.y*r; xa[6]=oth.z*r; xa[7]=oth.w*r;
        } else {
            xa[0]=oth.x*r; xa[1]=oth.y*r; xa[2]=oth.z*r; xa[3]=oth.w*r;
            xa[4]=acc.x*r; xa[5]=acc.y*r; xa[6]=acc.z*r; xa[7]=acc.w*r;
        }
#pragma unroll
        for (int k = 0; k < 8; k++) {
            v0 += xa[k] * w1c0[k];
            v1 += xa[k] * w1c1[k];
        }
        ((unsigned int*)y1)[(size_t)d * 64 + lane] = pack_bf2(v0, v1);
    }
    // block BN stat partials (deterministic: fixed wave order)
    __shared__ float sred[4][64][2];
    sred[q][lane][0] = nok ? v0 : 0.f;
    sred[q][lane][1] = nok ? v1 : 0.f;
    __syncthreads();
    if (t < 128) {
        int ln = t >> 1, cp = t & 1;
        Psum[blockIdx.x * 128 + t] =
            ((sred[0][ln][cp] + sred[1][ln][cp]) + sred[2][ln][cp]) + sred[3][ln][cp];
    }
    __syncthreads();
    sred[q][lane][0] = nok ? v0 * v0 : 0.f;
    sred[q][lane][1] = nok ? v1 * v1 : 0.f;
    __syncthreads();
    if (t < 128) {
        int ln = t >> 1, cp = t & 1;
        Psq[blockIdx.x * 128 + t] =
            ((sred[0][ln][cp] + sred[1][ln][cp]) + sred[2][ln][cp]) + sred[3][ln][cp];
    }
}

// ---- deterministic two-stage partial reduction ----
__global__ __launch_bounds__(256)
void k_reduce_a(const float* __restrict__ Psum, const float* __restrict__ Psq,
                int nIn, int chunk,
                float* __restrict__ Qsum, float* __restrict__ Qsq) {
    int j = threadIdx.x & 127;
    int h = threadIdx.x >> 7;
    int u = blockIdx.x * 2 + h;
    int b0 = u * chunk, b1 = min(b0 + chunk, nIn);
    float s = 0.f, q = 0.f;
#pragma unroll 8
    for (int b = b0; b < b1; b++) {
        s += Psum[b * 128 + j];
        q += Psq[b * 128 + j];
    }
    Qsum[u * 128 + j] = s;
    Qsq[u * 128 + j] = q;
}

__global__ __launch_bounds__(512)
void k_reduce_b(const float* __restrict__ Qsum, const float* __restrict__ Qsq,
                const float* __restrict__ gamma, const float* __restrict__ beta,
                float* __restrict__ scale, float* __restrict__ shift) {
    int j = threadIdx.x & 127;
    int g = threadIdx.x >> 7;
    float s = 0.f, q = 0.f;
#pragma unroll
    for (int u = g * 8; u < g * 8 + 8; u++) {
        s += Qsum[u * 128 + j];
        q += Qsq[u * 128 + j];
    }
    __shared__ float Ls[4][128], Lq[4][128];
    Ls[g][j] = s; Lq[g][j] = q;
    __syncthreads();
    if (g == 0) {
        float st = ((Ls[0][j] + Ls[1][j]) + Ls[2][j]) + Ls[3][j];
        float qt = ((Lq[0][j] + Lq[1][j]) + Lq[2][j]) + Lq[3][j];
        float mu = st * (1.f / N_NODES);
        float var = qt * (1.f / N_NODES) - mu * mu;
        float rs = rsqrtf(var + BN_EPS);
        float ga = gamma[j];
        scale[j] = rs * ga;
        shift[j] = beta[j] - mu * rs * ga;
    }
}

// ===== MFMA GEMM v2: direct-A from global, prestaged bf16 B =====
template<int NCV, bool ATT>
__global__ __launch_bounds__(256)
void k_gemm_mfma(const bf16* __restrict__ Yin,
                 const float* __restrict__ scale, const float* __restrict__ shift,
                 const bf16* __restrict__ Wt_g,
                 bf16* __restrict__ hout,
                 const float* __restrict__ w2s, const float* __restrict__ w2d,
                 float* __restrict__ fs, float* __restrict__ fd) {
    constexpr int NT = NCV / 16;
    __shared__ bf16 Wt[NCV * 136];   // [n][k], pad 136 -> 2-way (free) on frag reads
    __shared__ float scb[128], shb[128];
    const int t = threadIdx.x;
    for (int idx = t; idx < NCV * 16; idx += 256) {
        int n = idx >> 4, c = idx & 15;
        *(u32x4*)&Wt[n * 136 + c * 8] = *(const u32x4*)&Wt_g[n * 128 + c * 8];
    }
    if (t < 128) { scb[t] = scale[t]; shb[t] = shift[t]; }
    const int lane = t & 63;
    const int m16 = lane & 15;
    const int g = lane >> 4;        // k-chunk / output quad
    const int rg = t >> 6;          // wave id
    short8 attb[4];
    if constexpr (ATT) {
#pragma unroll
        for (int kk = 0; kk < 4; kk++) {
            union { short8 s; unsigned int u[4]; } pk;
            if (m16 < 2) {
                const float* wv = (m16 == 0) ? w2s : w2d;
                const float4 f0 = *(const float4*)&wv[kk * 32 + g * 8];
                const float4 f1 = *(const float4*)&wv[kk * 32 + g * 8 + 4];
                pk.u[0] = pack_bf2(f0.x, f0.y);
                pk.u[1] = pack_bf2(f0.z, f0.w);
                pk.u[2] = pack_bf2(f1.x, f1.y);
                pk.u[3] = pack_bf2(f1.z, f1.w);
            } else {
                pk.u[0] = pk.u[1] = pk.u[2] = pk.u[3] = 0u;
            }
            attb[kk] = pk.s;
        }
    }
    __syncthreads();

    const int row0 = blockIdx.x * 64;
    const int arow = row0 + rg * 16 + m16;
    const bool rok = arow < N_NODES;
    f32x4 acc[NT];
#pragma unroll
    for (int c = 0; c < NT; c++) acc[c] = (f32x4){0.f, 0.f, 0.f, 0.f};
    f32x4 accA = (f32x4){0.f, 0.f, 0.f, 0.f};
#pragma unroll
    for (int kk = 0; kk < 4; kk++) {
        u32x4 u4 = rok
            ? *(const u32x4*)&((const unsigned int*)Yin)[(size_t)arow * 64 + kk * 16 + g * 4]
            : (u32x4){0u, 0u, 0u, 0u};
        const float4 s0 = *(const float4*)&scb[kk * 32 + g * 8];
        const float4 s1 = *(const float4*)&scb[kk * 32 + g * 8 + 4];
        const float4 h0 = *(const float4*)&shb[kk * 32 + g * 8];
        const float4 h1 = *(const float4*)&shb[kk * 32 + g * 8 + 4];
        const float scv[8] = {s0.x, s0.y, s0.z, s0.w, s1.x, s1.y, s1.z, s1.w};
        const float shv[8] = {h0.x, h0.y, h0.z, h0.w, h1.x, h1.y, h1.z, h1.w};
        union { short8 s; unsigned int u[4]; } A;
#pragma unroll
        for (int fq = 0; fq < 4; fq++) {
            unsigned int u = u4[fq];
            float v0 = bfbits2f(u & 0xFFFF) * scv[2*fq]   + shv[2*fq];   v0 = v0 > 0.f ? v0 : 0.01f * v0;
            float v1 = bfbits2f(u >> 16)    * scv[2*fq+1] + shv[2*fq+1]; v1 = v1 > 0.f ? v1 : 0.01f * v1;
            A.u[fq] = pack_bf2(v0, v1);
        }
#pragma unroll
        for (int c = 0; c < NT; c++) {
            short8 bfr = *(const short8*)&Wt[(c * 16 + m16) * 136 + kk * 32 + g * 8];
            acc[c] = __builtin_amdgcn_mfma_f32_16x16x32_bf16(A.s, bfr, acc[c], 0, 0, 0);
        }
        if constexpr (ATT)
            accA = __builtin_amdgcn_mfma_f32_16x16x32_bf16(A.s, attb[kk], accA, 0, 0, 0);
    }
    const int orow = row0 + rg * 16 + g * 4;
#pragma unroll
    for (int c = 0; c < NT; c++) {
#pragma unroll
        for (int r = 0; r < 4; r++) {
            int grow = orow + r;
            if (grow < N_NODES)
                hout[(size_t)grow * 128 + c * 16 + m16] = __float2bfloat16(acc[c][r]);
        }
    }
    if constexpr (ATT) {
        if (m16 < 2) {
            float* o = (m16 == 0) ? fs : fd;
#pragma unroll
            for (int r = 0; r < 4; r++) {
                int grow = orow + r;
                if (grow < N_NODES) o[grow] = accA[r];
            }
        }
    }
}

// ===== attention gather, 4-edges-per-wave dwordx4 + fused BN stats =====
__global__ __launch_bounds__(256)
void k_gather_attn_bf(const int* __restrict__ cnt, const unsigned int* __restrict__ bucket,
                      const float* __restrict__ fs, const float* __restrict__ fd,
                      const bf16* __restrict__ h, bf16* __restrict__ y,
                      float* __restrict__ Psum, float* __restrict__ Psq) {
    const int xcd = blockIdx.x & 7;
    const int wb  = blockIdx.x >> 3;          // 0..399
    const int t = threadIdx.x;
    const int q = t >> 6;                     // wave 0..3
    const int lane = t & 63;
    const int grp = lane >> 4;                // edge group 0..3
    const int l = lane & 15;                  // 16B chunk id (8 feats)
    __shared__ int s_idx[4][CAP];
    __shared__ float s_e[4][CAP];
    __shared__ float sred[4][16][8];
    float ls[8], lq[8];
#pragma unroll
    for (int i = 0; i < 8; i++) { ls[i] = 0.f; lq[i] = 0.f; }

    for (int it = 0; it < ATT_IT; it++) {
        const int ni = (wb + it * 400) * 4 + q;       // wave-uniform
        if (ni >= NODE_RANGE) continue;               // no barriers inside
        const int d = xcd * NODE_RANGE + ni;
        const int deg = min(cnt[d], CAP);
        const float fdd = fd[d];
        if (lane < deg) {
            int s = bucket[d * CAP + lane] >> 15;
            float f = fs[s] + fdd;
            float lr = f > 0.f ? f : 0.2f * f;
            s_idx[q][lane] = s;
            s_e[q][lane] = __expf(-lr);
        }
        float a[8];
#pragma unroll
        for (int i = 0; i < 8; i++) a[i] = 0.f;
        float den = 0.f;
#pragma unroll 4
        for (int base = 0; base < deg; base += 4) {
            int k = base + grp;
            bool ev = k < deg;
            int kk = ev ? k : 0;
            float e = ev ? s_e[q][kk] : 0.f;
            int sidx = s_idx[q][kk];
            u32x4 u4 = *(const u32x4*)&((const unsigned int*)h)[(size_t)sidx * 64 + l * 4];
            den += e;
#pragma unroll
            for (int fq = 0; fq < 4; fq++) {
                unsigned int u = u4[fq];
                a[2*fq]   += e * bfbits2f(u & 0xFFFF);
                a[2*fq+1] += e * bfbits2f(u >> 16);
            }
        }
        // group reduce: xor 16, 32 (same-l lanes only)
#pragma unroll
        for (int off = 16; off < 64; off <<= 1) {
#pragma unroll
            for (int i = 0; i < 8; i++) a[i] += __shfl_xor(a[i], off);
            den += __shfl_xor(den, off);
        }
        float r = 1.f / (den + SEG_EPS);
        if (lane < 16) {
            u32x4 pk;
#pragma unroll
            for (int fq = 0; fq < 4; fq++) {
                float v0 = a[2*fq] * r, v1 = a[2*fq+1] * r;
                pk[fq] = pack_bf2(v0, v1);
                ls[2*fq] += v0;   lq[2*fq] += v0 * v0;
                ls[2*fq+1] += v1; lq[2*fq+1] += v1 * v1;
            }
            *(u32x4*)&((unsigned int*)y)[(size_t)d * 64 + l * 4] = pk;
        }
    }
    // block-wide stat partials
    if (lane < 16) {
#pragma unroll
        for (int i = 0; i < 8; i++) sred[q][l][i] = ls[i];
    }
    __syncthreads();
    if (t < 128) {
        int l16 = t >> 3, i8 = t & 7;
        Psum[blockIdx.x * 128 + t] =
            ((sred[0][l16][i8] + sred[1][l16][i8]) + sred[2][l16][i8]) + sred[3][l16][i8];
    }
    __syncthreads();
    if (lane < 16) {
#pragma unroll
        for (int i = 0; i < 8; i++) sred[q][l][i] = lq[i];
    }
    __syncthreads();
    if (t < 128) {
        int l16 = t >> 3, i8 = t & 7;
        Psq[blockIdx.x * 128 + t] =
            ((sred[0][l16][i8] + sred[1][l16][i8]) + sred[2][l16][i8]) + sred[3][l16][i8];
    }
}

// ===== final gather + epilogue, 4-edges-per-wave dwordx4 (sup stride 128) =====
__global__ __launch_bounds__(256)
void k_gather_out_bf(const int* __restrict__ cnt, const unsigned int* __restrict__ bucket,
                     const bf16* __restrict__ sup, const float* __restrict__ bg,
                     float* __restrict__ out) {
    const int xcd = blockIdx.x & 7;
    const int wb  = blockIdx.x >> 3;
    const int ni  = wb * 4 + (threadIdx.x >> 6);      // wave-uniform
    if (ni >= NODE_RANGE) return;
    const int d = xcd * NODE_RANGE + ni;
    const int t = threadIdx.x;
    const int q = t >> 6;
    const int lane = t & 63;
    const int grp = lane >> 4;
    const int l = lane & 15;
    __shared__ int s_idx[4][CAP];
    __shared__ float s_w[4][CAP];
    const int deg = min(cnt[d], CAP);
    if (lane < deg) {
        unsigned int b = bucket[d * CAP + lane];
        s_idx[q][lane] = b >> 15;
        s_w[q][lane] = (float)(b & 0x7FFF) * (1.f / (32767.f * 3.f));
    }
    float a[8];
#pragma unroll
    for (int i = 0; i < 8; i++) a[i] = 0.f;
#pragma unroll 4
    for (int base = 0; base < deg; base += 4) {
        int k = base + grp;
        bool ev = k < deg;
        int kk = ev ? k : 0;
        float w = ev ? s_w[q][kk] : 0.f;
        int sidx = s_idx[q][kk];
        u32x4 u4 = *(const u32x4*)&((const unsigned int*)sup)[(size_t)sidx * 64 + l * 4];
#pragma unroll
        for (int fq = 0; fq < 4; fq++) {
            unsigned int u = u4[fq];
            a[2*fq]   += w * bfbits2f(u & 0xFFFF);
            a[2*fq+1] += w * bfbits2f(u >> 16);
        }
    }
#pragma unroll
    for (int off = 16; off < 64; off <<= 1) {
#pragma unroll
        for (int i = 0; i < 8; i++) a[i] += __shfl_xor(a[i], off);
    }
    if (l < 14) {     // 14 chunks x 8 = 112 cols (chunks 14,15 are pad)
        u32x4 us = *(const u32x4*)&((const unsigned int*)sup)[(size_t)d * 64 + l * 4];
        const float4 b0 = *(const float4*)&bg[l * 8];
        const float4 b1 = *(const float4*)&bg[l * 8 + 4];
        float4 o0, o1;
        o0.x = a[0] + bfbits2f(us[0] & 0xFFFF) * (2.f/3.f) + b0.x;
        o0.y = a[1] + bfbits2f(us[0] >> 16)    * (2.f/3.f) + b0.y;
        o0.z = a[2] + bfbits2f(us[1] & 0xFFFF) * (2.f/3.f) + b0.z;
        o0.w = a[3] + bfbits2f(us[1] >> 16)    * (2.f/3.f) + b0.w;
        o1.x = a[4] + bfbits2f(us[2] & 0xFFFF) * (2.f/3.f) + b1.x;
        o1.y = a[5] + bfbits2f(us[2] >> 16)    * (2.f/3.f) + b1.y;
        o1.z = a[6] + bfbits2f(us[3] & 0xFFFF) * (2.f/3.f) + b1.z;
        o1.w = a[7] + bfbits2f(us[3] >> 16)    * (2.f/3.f) + b1.w;
        *(float4*)&out[(size_t)d * NCLASS + l * 8]     = o0;
        *(float4*)&out[(size_t)d * NCLASS + l * 8 + 4] = o1;
    }
}

extern "C" void kernel_launch(void* const* d_in, const int* in_sizes, int n_in,
                              void* d_out, int out_size, void* d_ws, size_t ws_size,
                              hipStream_t stream) {
    const float* x    = (const float*)d_in[0];
    const int*   ei   = (const int*)d_in[1];
    const float* ewt  = (const float*)d_in[2];
    const float* W1   = (const float*)d_in[3];
    const float* a1s  = (const float*)d_in[4];
    const float* a1d  = (const float*)d_in[5];
    const float* W2   = (const float*)d_in[6];
    const float* a2s  = (const float*)d_in[7];
    const float* a2d  = (const float*)d_in[8];
    const float* gam  = (const float*)d_in[9];
    const float* bet  = (const float*)d_in[10];
    const float* Wg   = (const float*)d_in[11];
    const float* bg   = (const float*)d_in[12];
    float* out = (float*)d_out;

    const int* src = ei;
    const int* dst = ei + N_EDGES;

    float* ws    = (float*)d_ws;
    bf16*  Yb    = (bf16*)ws;                       // [N,128] bf16 (y1, then y2)
    bf16*  Hb    = (bf16*)(ws + 3203072);           // [N,128] bf16 (h2 / support, stride 128)
    unsigned int* bucket = (unsigned int*)(ws + 6403072);   // [N*64] packed
    float* fs    = ws + 10003072;                   // [N]
    float* fd    = ws + 10053072;                   // [N]
    int*   cnt   = (int*)(ws + 10103072);           // [N]
    float* scale = ws + 10153072;                   // [128]
    float* shift = scale + 128;                     // [128]
    float* w2s   = shift + 128;                     // [128]
    float* w2d   = w2s + 128;                       // [128]
    float* Psum  = ws + 10153600;                   // [12800][128] = 1638400
    float* Psq   = Psum + 1638400;                  // [12800][128]
    float* Qsum  = Psq + 1638400;                   // [32][128]
    float* Qsq   = Qsum + 4096;                     // [32][128]
    bf16*  W2t   = (bf16*)(Qsq + 4096);             // [128][128] bf16 (8192 floats)
    bf16*  Wgt   = W2t + 16384;                     // [112][128] bf16 (7168 floats)
                                                    // ends ~13.45M floats (54MB) << 256MB ws

    // ---- bucketed CSR build + fsfd + weight prep (one launch) ----
    hipMemsetAsync(cnt, 0, (size_t)N_NODES * 4, stream);
    k_fill_fsfd<<<GRID_FILL, 256, 0, stream>>>(
        src, dst, ewt, cnt, bucket, x, W1, a1s, a1d, fs, fd,
        W2, a2s, a2d, w2s, w2d, Wg, W2t, Wgt);

    // ---- layer 1 (sort + gather + y1 + stats fused) ----
    k_sort_gather_y1<<<GATH_GRID, 256, 0, stream>>>(cnt, bucket, fs, fd, x, W1,
                                                    Yb, Psum, Psq);
    k_reduce_a<<<16, 256, 0, stream>>>(Psum, Psq, GATH_GRID, 400, Qsum, Qsq);
    k_reduce_b<<<1, 512, 0, stream>>>(Qsum, Qsq, gam, bet, scale, shift);

    // ---- layer 2 ----
    k_gemm_mfma<128, true><<<MACRO_TILES, 256, 0, stream>>>(Yb, scale, shift, W2t, Hb,
                                                            w2s, w2d, fs, fd);    // Hb = h2
    k_gather_attn_bf<<<ATT_GRID, 256, 0, stream>>>(cnt, bucket, fs, fd, Hb, Yb,
                                                   Psum, Psq);                    // Yb = y2 + stats
    k_reduce_a<<<16, 256, 0, stream>>>(Psum, Psq, ATT_GRID, 100, Qsum, Qsq);
    k_reduce_b<<<1, 512, 0, stream>>>(Qsum, Qsq, gam, bet, scale, shift);

    // ---- output head (support stored at stride 128 for aligned 16B gathers) ----
    k_gemm_mfma<112, false><<<MACRO_TILES, 256, 0, stream>>>(Yb, scale, shift, Wgt, Hb,
                                                             nullptr, nullptr, nullptr, nullptr);
    k_gather_out_bf<<<GATH_GRID, 256, 0, stream>>>(cnt, bucket, Hb, bg, out);
}

// Round 8
// 279.539 us; speedup vs baseline: 1.1842x; 1.0582x over previous
//
#include <hip/hip_runtime.h>
#include <hip/hip_bf16.h>

#define N_NODES 50000
#define N_EDGES 800000
#define NFEAT   8
#define NHID    128
#define NCLASS  112
#define SEG_EPS 1e-16f
#define BN_EPS  1e-5f
#define CAP     64
#define MACRO_TILES 782
#define NODE_RANGE 6250
#define FILL_CHUNK 2048
#define FILL_CHUNKS 391
#define FSFD_BLOCKS 196
#define SG_GRID 3200
#define SG_IT 4
#define ATT_GRID 3200
#define ATT_IT 4
#define GATH_GRID_OUT 12800

#define FILLB (FILL_CHUNKS * 8)
#define FSFD0 FILLB
#define W2P0  (FSFD0 + FSFD_BLOCKS)
#define W2T0  (W2P0 + 64)
#define WGT0  (W2T0 + 32)
#define GRID_FILL (WGT0 + 28)

typedef __hip_bfloat16 bf16;
typedef __attribute__((ext_vector_type(8))) short short8;
typedef __attribute__((ext_vector_type(4))) float f32x4;
typedef __attribute__((ext_vector_type(4))) unsigned int u32x4;

__device__ __forceinline__ float bfbits2f(unsigned int lo16) {
    union { unsigned int u; float f; } c; c.u = lo16 << 16; return c.f;
}

__device__ __forceinline__ unsigned int pack_bf2(float a, float b) {
    union { unsigned int u; bf16 h[2]; } t;
    t.h[0] = __float2bfloat16(a);
    t.h[1] = __float2bfloat16(b);
    return t.u;
}

__global__ __launch_bounds__(256)
void k_fill_fsfd(const int* __restrict__ src, const int* __restrict__ dst,
                 const float* __restrict__ ewt,
                 int* __restrict__ cnt, unsigned int* __restrict__ bucket,
                 const float* __restrict__ x, const float* __restrict__ W1,
                 const float* __restrict__ a1s, const float* __restrict__ a1d,
                 float* __restrict__ fs, float* __restrict__ fd,
                 const float* __restrict__ W2,
                 const float* __restrict__ a2s, const float* __restrict__ a2d,
                 float* __restrict__ w2s, float* __restrict__ w2d,
                 const float* __restrict__ Wg,
                 bf16* __restrict__ W2t, bf16* __restrict__ Wgt) {
    __shared__ float sw[16];
    __shared__ float ps[4], pd[4];
    const int t = threadIdx.x;
    if (blockIdx.x < FILLB) {
        const int range = blockIdx.x & 7;
        const int chunk = blockIdx.x >> 3;
        const int lo = range * NODE_RANGE, hi = lo + NODE_RANGE;
        const int e0 = chunk * FILL_CHUNK + t * 8;
        if (e0 >= N_EDGES) return;
        const int4 d0 = *(const int4*)&dst[e0];
        const int4 d1 = *(const int4*)&dst[e0 + 4];
        const int dd[8] = {d0.x, d0.y, d0.z, d0.w, d1.x, d1.y, d1.z, d1.w};
#pragma unroll
        for (int i = 0; i < 8; i++) {
            int d = dd[i];
            if (d < lo || d >= hi) continue;
            int e = e0 + i;
            int slot = atomicAdd(&cnt[d], 1);
            if (slot < CAP) {
                unsigned int iw = (unsigned int)(ewt[e] * 32767.f + 0.5f);
                bucket[d * CAP + slot] = ((unsigned int)src[e] << 15) | iw;
            }
        }
        return;
    }
    if (blockIdx.x < W2P0) {
        const int w = t >> 6, lane = t & 63;
#pragma unroll
        for (int dd = 0; dd < 4; dd++) {
            int dot = w + dd * 4;
            int k = dot & 7;
            const float* a = (dot < 8) ? a1s : a1d;
            float v = W1[k * NHID + lane] * a[lane] + W1[k * NHID + 64 + lane] * a[64 + lane];
#pragma unroll
            for (int off = 32; off > 0; off >>= 1) v += __shfl_down(v, off);
            if (lane == 0) sw[dot] = v;
        }
        __syncthreads();
        const int i = (blockIdx.x - FSFD0) * 256 + t;
        if (i < N_NODES) {
            const float4 x0 = ((const float4*)x)[i * 2];
            const float4 x1 = ((const float4*)x)[i * 2 + 1];
            fs[i] = x0.x*sw[0] + x0.y*sw[1] + x0.z*sw[2] + x0.w*sw[3]
                  + x1.x*sw[4] + x1.y*sw[5] + x1.z*sw[6] + x1.w*sw[7];
            fd[i] = x0.x*sw[8] + x0.y*sw[9] + x0.z*sw[10] + x0.w*sw[11]
                  + x1.x*sw[12] + x1.y*sw[13] + x1.z*sw[14] + x1.w*sw[15];
        }
        return;
    }
    if (blockIdx.x < W2T0) {
        const int k = (blockIdx.x - W2P0) * 2 + (t >> 7);
        const int n = t & 127;
        float wv = W2[k * NHID + n];
        float vs = wv * a2s[n], vd = wv * a2d[n];
#pragma unroll
        for (int off = 32; off > 0; off >>= 1) { vs += __shfl_down(vs, off); vd += __shfl_down(vd, off); }
        const int wid = t >> 6;
        if ((t & 63) == 0) { ps[wid] = vs; pd[wid] = vd; }
        __syncthreads();
        if ((t & 127) == 0) { w2s[k] = ps[wid] + ps[wid + 1]; w2d[k] = pd[wid] + pd[wid + 1]; }
        return;
    }
    if (blockIdx.x < WGT0) {
        const int n = (blockIdx.x - W2T0) * 4 + (t >> 6);
        const int k2 = (t & 63) * 2;
        *(unsigned int*)&W2t[n * 128 + k2] = pack_bf2(W2[k2 * NHID + n], W2[(k2 + 1) * NHID + n]);
        return;
    }
    const int n = (blockIdx.x - WGT0) * 4 + (t >> 6);
    const int k2 = (t & 63) * 2;
    *(unsigned int*)&Wgt[n * 128 + k2] = pack_bf2(Wg[k2 * NCLASS + n], Wg[(k2 + 1) * NCLASS + n]);
}

// ===== sort + gather + y1 + BN partials, grid-strided 3200 x 4 iters =====
__global__ __launch_bounds__(256)
void k_sort_gather_y1(const int* __restrict__ cnt, unsigned int* __restrict__ bucket,
                      const float* __restrict__ fs, const float* __restrict__ fd,
                      const float* __restrict__ x, const float* __restrict__ W1,
                      bf16* __restrict__ y1,
                      float* __restrict__ Psum, float* __restrict__ Psq) {
    const int xcd = blockIdx.x & 7;
    const int wb  = blockIdx.x >> 3;
    const int t = threadIdx.x;
    const int q = t >> 6;
    const int lane = t & 63;
    float w1c0[8], w1c1[8];
#pragma unroll
    for (int k = 0; k < 8; k++) {
        const float2 wv = *(const float2*)&W1[k * NHID + 2 * lane];
        w1c0[k] = wv.x; w1c1[k] = wv.y;
    }
    float ls0 = 0.f, ls1 = 0.f, lq0 = 0.f, lq1 = 0.f;
    for (int it = 0; it < SG_IT; it++) {
        const int ni = (wb + it * 400) * 4 + q;
        if (ni >= NODE_RANGE) continue;
        const int d = xcd * NODE_RANGE + ni;
        const int deg = min(cnt[d], CAP);
        unsigned int v = (lane < deg) ? bucket[d * CAP + lane] : 0xFFFFFFFFu;
#pragma unroll
        for (int k = 2; k <= 64; k <<= 1) {
#pragma unroll
            for (int s = k >> 1; s > 0; s >>= 1) {
                unsigned int o = (unsigned int)__shfl_xor((int)v, s);
                bool keepmin = ((lane & s) == 0) == ((lane & k) == 0);
                v = keepmin ? min(v, o) : max(v, o);
            }
        }
        if (lane < deg) bucket[d * CAP + lane] = v;
        const int epair = lane >> 1;
        const int half  = lane & 1;
        const float fdd = fd[d];
        float4 acc = {0.f, 0.f, 0.f, 0.f};
        float den = 0.f;
        for (int base = 0; base < deg; base += 32) {
            int e = base + epair;
            unsigned int u = (unsigned int)__shfl((int)v, e);
            if (e < deg) {
                int s = u >> 15;
                float f = fs[s] + fdd;
                float lr = f > 0.f ? f : 0.2f * f;
                float c = __expf(-lr);
                if (half == 0) den += c;
                const float4 xv = *(const float4*)&x[s * NFEAT + half * 4];
                acc.x += c * xv.x; acc.y += c * xv.y; acc.z += c * xv.z; acc.w += c * xv.w;
            }
        }
#pragma unroll
        for (int off = 2; off < 64; off <<= 1) {
            acc.x += __shfl_xor(acc.x, off);
            acc.y += __shfl_xor(acc.y, off);
            acc.z += __shfl_xor(acc.z, off);
            acc.w += __shfl_xor(acc.w, off);
            den   += __shfl_xor(den, off);
        }
        den += __shfl_xor(den, 1);
        float4 oth;
        oth.x = __shfl_xor(acc.x, 1);
        oth.y = __shfl_xor(acc.y, 1);
        oth.z = __shfl_xor(acc.z, 1);
        oth.w = __shfl_xor(acc.w, 1);
        const float r = 1.f / (den + SEG_EPS);
        float xa[8];
        if ((lane & 1) == 0) {
            xa[0]=acc.x*r; xa[1]=acc.y*r; xa[2]=acc.z*r; xa[3]=acc.w*r;
            xa[4]=oth.x*r; xa[5]=oth.y*r; xa[6]=oth.z*r; xa[7]=oth.w*r;
        } else {
            xa[0]=oth.x*r; xa[1]=oth.y*r; xa[2]=oth.z*r; xa[3]=oth.w*r;
            xa[4]=acc.x*r; xa[5]=acc.y*r; xa[6]=acc.z*r; xa[7]=acc.w*r;
        }
        float v0 = 0.f, v1 = 0.f;
#pragma unroll
        for (int k = 0; k < 8; k++) {
            v0 += xa[k] * w1c0[k];
            v1 += xa[k] * w1c1[k];
        }
        ((unsigned int*)y1)[(size_t)d * 64 + lane] = pack_bf2(v0, v1);
        ls0 += v0; lq0 += v0 * v0;
        ls1 += v1; lq1 += v1 * v1;
    }
    __shared__ float sred[4][64][2];
    sred[q][lane][0] = ls0;
    sred[q][lane][1] = ls1;
    __syncthreads();
    if (t < 128) {
        int ln = t >> 1, cp = t & 1;
        Psum[blockIdx.x * 128 + t] =
            ((sred[0][ln][cp] + sred[1][ln][cp]) + sred[2][ln][cp]) + sred[3][ln][cp];
    }
    __syncthreads();
    sred[q][lane][0] = lq0;
    sred[q][lane][1] = lq1;
    __syncthreads();
    if (t < 128) {
        int ln = t >> 1, cp = t & 1;
        Psq[blockIdx.x * 128 + t] =
            ((sred[0][ln][cp] + sred[1][ln][cp]) + sred[2][ln][cp]) + sred[3][ln][cp];
    }
}

// ===== fused BN reduction: 16 workers + 1 spin-wait finalizer =====
__global__ __launch_bounds__(256)
void k_reduce_fused(const float* __restrict__ Psum, const float* __restrict__ Psq,
                    int nIn, int chunk,
                    float* __restrict__ Qsum, float* __restrict__ Qsq,
                    const float* __restrict__ gamma, const float* __restrict__ beta,
                    float* __restrict__ scale, float* __restrict__ shift,
                    int* __restrict__ flag) {
    const int t = threadIdx.x;
    if (blockIdx.x < 16) {
        const int j = t & 127;
        const int h = t >> 7;
        const int u = blockIdx.x * 2 + h;
        const int b0 = u * chunk, b1 = min(b0 + chunk, nIn);
        float s = 0.f, q = 0.f;
#pragma unroll 8
        for (int b = b0; b < b1; b++) {
            s += Psum[b * 128 + j];
            q += Psq[b * 128 + j];
        }
        Qsum[u * 128 + j] = s;
        Qsq[u * 128 + j] = q;
        __threadfence();
        __syncthreads();
        if (t == 0) atomicAdd(flag, 1);
        return;
    }
    if (t == 0) { while (atomicAdd(flag, 0) < 16) { } }
    __syncthreads();
    __threadfence();
    const int j = t & 127;
    const int g = t >> 7;
    float s = 0.f, q = 0.f;
#pragma unroll
    for (int u = g * 16; u < g * 16 + 16; u++) {
        s += Qsum[u * 128 + j];
        q += Qsq[u * 128 + j];
    }
    __shared__ float Ls[2][128], Lq[2][128];
    Ls[g][j] = s; Lq[g][j] = q;
    __syncthreads();
    if (g == 0) {
        float st = Ls[0][j] + Ls[1][j];
        float qt = Lq[0][j] + Lq[1][j];
        float mu = st * (1.f / N_NODES);
        float var = qt * (1.f / N_NODES) - mu * mu;
        float rs = rsqrtf(var + BN_EPS);
        float ga = gamma[j];
        scale[j] = rs * ga;
        shift[j] = beta[j] - mu * rs * ga;
    }
    __syncthreads();
    if (t == 0) atomicExch(flag, 0);
}

// ===== MFMA GEMM v2: direct-A from global, prestaged bf16 B =====
template<int NCV, bool ATT>
__global__ __launch_bounds__(256)
void k_gemm_mfma(const bf16* __restrict__ Yin,
                 const float* __restrict__ scale, const float* __restrict__ shift,
                 const bf16* __restrict__ Wt_g,
                 bf16* __restrict__ hout,
                 const float* __restrict__ w2s, const float* __restrict__ w2d,
                 float* __restrict__ fs, float* __restrict__ fd) {
    constexpr int NT = NCV / 16;
    __shared__ bf16 Wt[NCV * 136];
    __shared__ float scb[128], shb[128];
    const int t = threadIdx.x;
    for (int idx = t; idx < NCV * 16; idx += 256) {
        int n = idx >> 4, c = idx & 15;
        *(u32x4*)&Wt[n * 136 + c * 8] = *(const u32x4*)&Wt_g[n * 128 + c * 8];
    }
    if (t < 128) { scb[t] = scale[t]; shb[t] = shift[t]; }
    const int lane = t & 63;
    const int m16 = lane & 15;
    const int g = lane >> 4;
    const int rg = t >> 6;
    short8 attb[4];
    if constexpr (ATT) {
#pragma unroll
        for (int kk = 0; kk < 4; kk++) {
            union { short8 s; unsigned int u[4]; } pk;
            if (m16 < 2) {
                const float* wv = (m16 == 0) ? w2s : w2d;
                const float4 f0 = *(const float4*)&wv[kk * 32 + g * 8];
                const float4 f1 = *(const float4*)&wv[kk * 32 + g * 8 + 4];
                pk.u[0] = pack_bf2(f0.x, f0.y);
                pk.u[1] = pack_bf2(f0.z, f0.w);
                pk.u[2] = pack_bf2(f1.x, f1.y);
                pk.u[3] = pack_bf2(f1.z, f1.w);
            } else {
                pk.u[0] = pk.u[1] = pk.u[2] = pk.u[3] = 0u;
            }
            attb[kk] = pk.s;
        }
    }
    __syncthreads();

    const int row0 = blockIdx.x * 64;
    const int arow = row0 + rg * 16 + m16;
    const bool rok = arow < N_NODES;
    f32x4 acc[NT];
#pragma unroll
    for (int c = 0; c < NT; c++) acc[c] = (f32x4){0.f, 0.f, 0.f, 0.f};
    f32x4 accA = (f32x4){0.f, 0.f, 0.f, 0.f};
#pragma unroll
    for (int kk = 0; kk < 4; kk++) {
        u32x4 u4 = rok
            ? *(const u32x4*)&((const unsigned int*)Yin)[(size_t)arow * 64 + kk * 16 + g * 4]
            : (u32x4){0u, 0u, 0u, 0u};
        const float4 s0 = *(const float4*)&scb[kk * 32 + g * 8];
        const float4 s1 = *(const float4*)&scb[kk * 32 + g * 8 + 4];
        const float4 h0 = *(const float4*)&shb[kk * 32 + g * 8];
        const float4 h1 = *(const float4*)&shb[kk * 32 + g * 8 + 4];
        const float scv[8] = {s0.x, s0.y, s0.z, s0.w, s1.x, s1.y, s1.z, s1.w};
        const float shv[8] = {h0.x, h0.y, h0.z, h0.w, h1.x, h1.y, h1.z, h1.w};
        union { short8 s; unsigned int u[4]; } A;
#pragma unroll
        for (int fq = 0; fq < 4; fq++) {
            unsigned int u = u4[fq];
            float v0 = bfbits2f(u & 0xFFFF) * scv[2*fq]   + shv[2*fq];   v0 = v0 > 0.f ? v0 : 0.01f * v0;
            float v1 = bfbits2f(u >> 16)    * scv[2*fq+1] + shv[2*fq+1]; v1 = v1 > 0.f ? v1 : 0.01f * v1;
            A.u[fq] = pack_bf2(v0, v1);
        }
#pragma unroll
        for (int c = 0; c < NT; c++) {
            short8 bfr = *(const short8*)&Wt[(c * 16 + m16) * 136 + kk * 32 + g * 8];
            acc[c] = __builtin_amdgcn_mfma_f32_16x16x32_bf16(A.s, bfr, acc[c], 0, 0, 0);
        }
        if constexpr (ATT)
            accA = __builtin_amdgcn_mfma_f32_16x16x32_bf16(A.s, attb[kk], accA, 0, 0, 0);
    }
    const int orow = row0 + rg * 16 + g * 4;
#pragma unroll
    for (int c = 0; c < NT; c++) {
#pragma unroll
        for (int r = 0; r < 4; r++) {
            int grow = orow + r;
            if (grow < N_NODES)
                hout[(size_t)grow * 128 + c * 16 + m16] = __float2bfloat16(acc[c][r]);
        }
    }
    if constexpr (ATT) {
        if (m16 < 2) {
            float* o = (m16 == 0) ? fs : fd;
#pragma unroll
            for (int r = 0; r < 4; r++) {
                int grow = orow + r;
                if (grow < N_NODES) o[grow] = accA[r];
            }
        }
    }
}

// ===== attention gather, 4-edges-per-wave dwordx4 + fused BN stats =====
__global__ __launch_bounds__(256)
void k_gather_attn_bf(const int* __restrict__ cnt, const unsigned int* __restrict__ bucket,
                      const float* __restrict__ fs, const float* __restrict__ fd,
                      const bf16* __restrict__ h, bf16* __restrict__ y,
                      float* __restrict__ Psum, float* __restrict__ Psq) {
    const int xcd = blockIdx.x & 7;
    const int wb  = blockIdx.x >> 3;
    const int t = threadIdx.x;
    const int q = t >> 6;
    const int lane = t & 63;
    const int grp = lane >> 4;
    const int l = lane & 15;
    __shared__ int s_idx[4][CAP];
    __shared__ float s_e[4][CAP];
    __shared__ float sred[4][16][8];
    float ls[8], lq[8];
#pragma unroll
    for (int i = 0; i < 8; i++) { ls[i] = 0.f; lq[i] = 0.f; }

    for (int it = 0; it < ATT_IT; it++) {
        const int ni = (wb + it * 400) * 4 + q;
        if (ni >= NODE_RANGE) continue;
        const int d = xcd * NODE_RANGE + ni;
        const int deg = min(cnt[d], CAP);
        const float fdd = fd[d];
        if (lane < deg) {
            int s = bucket[d * CAP + lane] >> 15;
            float f = fs[s] + fdd;
            float lr = f > 0.f ? f : 0.2f * f;
            s_idx[q][lane] = s;
            s_e[q][lane] = __expf(-lr);
        }
        float a[8];
#pragma unroll
        for (int i = 0; i < 8; i++) a[i] = 0.f;
        float den = 0.f;
#pragma unroll 4
        for (int base = 0; base < deg; base += 4) {
            int k = base + grp;
            bool ev = k < deg;
            int kk = ev ? k : 0;
            float e = ev ? s_e[q][kk] : 0.f;
            int sidx = s_idx[q][kk];
            u32x4 u4 = *(const u32x4*)&((const unsigned int*)h)[(size_t)sidx * 64 + l * 4];
            den += e;
#pragma unroll
            for (int fq = 0; fq < 4; fq++) {
                unsigned int u = u4[fq];
                a[2*fq]   += e * bfbits2f(u & 0xFFFF);
                a[2*fq+1] += e * bfbits2f(u >> 16);
            }
        }
#pragma unroll
        for (int off = 16; off < 64; off <<= 1) {
#pragma unroll
            for (int i = 0; i < 8; i++) a[i] += __shfl_xor(a[i], off);
            den += __shfl_xor(den, off);
        }
        float r = 1.f / (den + SEG_EPS);
        if (lane < 16) {
            u32x4 pk;
#pragma unroll
            for (int fq = 0; fq < 4; fq++) {
                float v0 = a[2*fq] * r, v1 = a[2*fq+1] * r;
                pk[fq] = pack_bf2(v0, v1);
                ls[2*fq] += v0;   lq[2*fq] += v0 * v0;
                ls[2*fq+1] += v1; lq[2*fq+1] += v1 * v1;
            }
            *(u32x4*)&((unsigned int*)y)[(size_t)d * 64 + l * 4] = pk;
        }
    }
    if (lane < 16) {
#pragma unroll
        for (int i = 0; i < 8; i++) sred[q][l][i] = ls[i];
    }
    __syncthreads();
    if (t < 128) {
        int l16 = t >> 3, i8 = t & 7;
        Psum[blockIdx.x * 128 + t] =
            ((sred[0][l16][i8] + sred[1][l16][i8]) + sred[2][l16][i8]) + sred[3][l16][i8];
    }
    __syncthreads();
    if (lane < 16) {
#pragma unroll
        for (int i = 0; i < 8; i++) sred[q][l][i] = lq[i];
    }
    __syncthreads();
    if (t < 128) {
        int l16 = t >> 3, i8 = t & 7;
        Psq[blockIdx.x * 128 + t] =
            ((sred[0][l16][i8] + sred[1][l16][i8]) + sred[2][l16][i8]) + sred[3][l16][i8];
    }
}

// ===== final gather + epilogue =====
__global__ __launch_bounds__(256)
void k_gather_out_bf(const int* __restrict__ cnt, const unsigned int* __restrict__ bucket,
                     const bf16* __restrict__ sup, const float* __restrict__ bg,
                     float* __restrict__ out) {
    const int xcd = blockIdx.x & 7;
    const int wb  = blockIdx.x >> 3;
    const int ni  = wb * 4 + (threadIdx.x >> 6);
    if (ni >= NODE_RANGE) return;
    const int d = xcd * NODE_RANGE + ni;
    const int t = threadIdx.x;
    const int q = t >> 6;
    const int lane = t & 63;
    const int grp = lane >> 4;
    const int l = lane & 15;
    __shared__ int s_idx[4][CAP];
    __shared__ float s_w[4][CAP];
    const int deg = min(cnt[d], CAP);
    if (lane < deg) {
        unsigned int b = bucket[d * CAP + lane];
        s_idx[q][lane] = b >> 15;
        s_w[q][lane] = (float)(b & 0x7FFF) * (1.f / (32767.f * 3.f));
    }
    float a[8];
#pragma unroll
    for (int i = 0; i < 8; i++) a[i] = 0.f;
#pragma unroll 4
    for (int base = 0; base < deg; base += 4) {
        int k = base + grp;
        bool ev = k < deg;
        int kk = ev ? k : 0;
        float w = ev ? s_w[q][kk] : 0.f;
        int sidx = s_idx[q][kk];
        u32x4 u4 = *(const u32x4*)&((const unsigned int*)sup)[(size_t)sidx * 64 + l * 4];
#pragma unroll
        for (int fq = 0; fq < 4; fq++) {
            unsigned int u = u4[fq];
            a[2*fq]   += w * bfbits2f(u & 0xFFFF);
            a[2*fq+1] += w * bfbits2f(u >> 16);
        }
    }
#pragma unroll
    for (int off = 16; off < 64; off <<= 1) {
#pragma unroll
        for (int i = 0; i < 8; i++) a[i] += __shfl_xor(a[i], off);
    }
    if (l < 14) {
        u32x4 us = *(const u32x4*)&((const unsigned int*)sup)[(size_t)d * 64 + l * 4];
        const float4 b0 = *(const float4*)&bg[l * 8];
        const float4 b1 = *(const float4*)&bg[l * 8 + 4];
        float4 o0, o1;
        o0.x = a[0] + bfbits2f(us[0] & 0xFFFF) * (2.f/3.f) + b0.x;
        o0.y = a[1] + bfbits2f(us[0] >> 16)    * (2.f/3.f) + b0.y;
        o0.z = a[2] + bfbits2f(us[1] & 0xFFFF) * (2.f/3.f) + b0.z;
        o0.w = a[3] + bfbits2f(us[1] >> 16)    * (2.f/3.f) + b0.w;
        o1.x = a[4] + bfbits2f(us[2] & 0xFFFF) * (2.f/3.f) + b1.x;
        o1.y = a[5] + bfbits2f(us[2] >> 16)    * (2.f/3.f) + b1.y;
        o1.z = a[6] + bfbits2f(us[3] & 0xFFFF) * (2.f/3.f) + b1.z;
        o1.w = a[7] + bfbits2f(us[3] >> 16)    * (2.f/3.f) + b1.w;
        *(float4*)&out[(size_t)d * NCLASS + l * 8]     = o0;
        *(float4*)&out[(size_t)d * NCLASS + l * 8 + 4] = o1;
    }
}

extern "C" void kernel_launch(void* const* d_in, const int* in_sizes, int n_in,
                              void* d_out, int out_size, void* d_ws, size_t ws_size,
                              hipStream_t stream) {
    const float* x    = (const float*)d_in[0];
    const int*   ei   = (const int*)d_in[1];
    const float* ewt  = (const float*)d_in[2];
    const float* W1   = (const float*)d_in[3];
    const float* a1s  = (const float*)d_in[4];
    const float* a1d  = (const float*)d_in[5];
    const float* W2   = (const float*)d_in[6];
    const float* a2s  = (const float*)d_in[7];
    const float* a2d  = (const float*)d_in[8];
    const float* gam  = (const float*)d_in[9];
    const float* bet  = (const float*)d_in[10];
    const float* Wg   = (const float*)d_in[11];
    const float* bg   = (const float*)d_in[12];
    float* out = (float*)d_out;

    const int* src = ei;
    const int* dst = ei + N_EDGES;

    float* ws    = (float*)d_ws;
    bf16*  Yb    = (bf16*)ws;                       // [N,128] bf16 (y1, then y2)
    bf16*  Hb    = (bf16*)(ws + 3203072);           // [N,128] bf16 (h2 / support)
    unsigned int* bucket = (unsigned int*)(ws + 6403072);   // [N*64] packed
    float* fs    = ws + 10003072;                   // [N]
    float* fd    = ws + 10053072;                   // [N]
    int*   cnt   = (int*)(ws + 10103072);           // [N]
    int*   flags = (int*)(ws + 10153072);           // [4] (covered by memset)
    float* scale = ws + 10153076;                   // [128] (16B-aligned)
    float* shift = scale + 128;                     // [128]
    float* w2s   = shift + 128;                     // [128]
    float* w2d   = w2s + 128;                       // [128] ends 10153588
    float* Psum  = ws + 10153600;                   // [3200][128]
    float* Psq   = Psum + 409600;                   // [3200][128]
    float* Qsum  = Psq + 409600;                    // [32][128]
    float* Qsq   = Qsum + 4096;                     // [32][128]
    bf16*  W2t   = (bf16*)(Qsq + 4096);             // [128][128] bf16
    bf16*  Wgt   = W2t + 16384;                     // [112][128] bf16

    // ---- bucketed CSR build + fsfd + weight prep (one launch) ----
    hipMemsetAsync(cnt, 0, (size_t)(N_NODES + 4) * 4, stream);   // cnt + flags
    k_fill_fsfd<<<GRID_FILL, 256, 0, stream>>>(
        src, dst, ewt, cnt, bucket, x, W1, a1s, a1d, fs, fd,
        W2, a2s, a2d, w2s, w2d, Wg, W2t, Wgt);

    // ---- layer 1 ----
    k_sort_gather_y1<<<SG_GRID, 256, 0, stream>>>(cnt, bucket, fs, fd, x, W1,
                                                  Yb, Psum, Psq);
    k_reduce_fused<<<17, 256, 0, stream>>>(Psum, Psq, SG_GRID, 100, Qsum, Qsq,
                                           gam, bet, scale, shift, flags + 0);

    // ---- layer 2 ----
    k_gemm_mfma<128, true><<<MACRO_TILES, 256, 0, stream>>>(Yb, scale, shift, W2t, Hb,
                                                            w2s, w2d, fs, fd);    // Hb = h2
    k_gather_attn_bf<<<ATT_GRID, 256, 0, stream>>>(cnt, bucket, fs, fd, Hb, Yb,
                                                   Psum, Psq);                    // Yb = y2 + stats
    k_reduce_fused<<<17, 256, 0, stream>>>(Psum, Psq, ATT_GRID, 100, Qsum, Qsq,
                                           gam, bet, scale, shift, flags + 1);

    // ---- output head ----
    k_gemm_mfma<112, false><<<MACRO_TILES, 256, 0, stream>>>(Yb, scale, shift, Wgt, Hb,
                                                             nullptr, nullptr, nullptr, nullptr);
    k_gather_out_bf<<<GATH_GRID_OUT, 256, 0, stream>>>(cnt, bucket, Hb, bg, out);
}

// Round 9
// 277.131 us; speedup vs baseline: 1.1945x; 1.0087x over previous
//
#include <hip/hip_runtime.h>
#include <hip/hip_bf16.h>

#define N_NODES 50000
#define N_EDGES 800000
#define NFEAT   8
#define NHID    128
#define NCLASS  112
#define SEG_EPS 1e-16f
#define BN_EPS  1e-5f
#define CAP     64
#define MACRO_TILES 782
#define NODE_RANGE 6250
#define FILL_CHUNK 2048
#define FILL_CHUNKS 391
#define FSFD_BLOCKS 196
#define SG_GRID 3200
#define SG_IT 4
#define ATT_GRID 3200
#define ATT_IT 4
#define OUT_GRID 3200
#define OUT_IT 4

#define FILLB (FILL_CHUNKS * 8)
#define FSFD0 FILLB
#define W2P0  (FSFD0 + FSFD_BLOCKS)
#define W2T0  (W2P0 + 64)
#define WGT0  (W2T0 + 32)
#define GRID_FILL (WGT0 + 28)

typedef __hip_bfloat16 bf16;
typedef __attribute__((ext_vector_type(8))) short short8;
typedef __attribute__((ext_vector_type(4))) float f32x4;
typedef __attribute__((ext_vector_type(4))) unsigned int u32x4;

__device__ __forceinline__ float bfbits2f(unsigned int lo16) {
    union { unsigned int u; float f; } c; c.u = lo16 << 16; return c.f;
}

__device__ __forceinline__ unsigned int pack_bf2(float a, float b) {
    union { unsigned int u; bf16 h[2]; } t;
    t.h[0] = __float2bfloat16(a);
    t.h[1] = __float2bfloat16(b);
    return t.u;
}

// ======= bucketed CSR build (XCD-partitioned, plain cached loads) =======
// fsfd blocks emit PACKED 64B rows xf[i] = {x[0..7], fs, fd, pad} so the
// layer-1 gather touches ONE cache line per edge instead of two (x + fs).
__global__ __launch_bounds__(256)
void k_fill_fsfd(const int* __restrict__ src, const int* __restrict__ dst,
                 const float* __restrict__ ewt,
                 int* __restrict__ cnt, unsigned int* __restrict__ bucket,
                 const float* __restrict__ x, const float* __restrict__ W1,
                 const float* __restrict__ a1s, const float* __restrict__ a1d,
                 float* __restrict__ xf,
                 const float* __restrict__ W2,
                 const float* __restrict__ a2s, const float* __restrict__ a2d,
                 float* __restrict__ w2s, float* __restrict__ w2d,
                 const float* __restrict__ Wg,
                 bf16* __restrict__ W2t, bf16* __restrict__ Wgt) {
    __shared__ float sw[16];
    __shared__ float ps[4], pd[4];
    const int t = threadIdx.x;
    if (blockIdx.x < FILLB) {
        const int range = blockIdx.x & 7;
        const int chunk = blockIdx.x >> 3;
        const int lo = range * NODE_RANGE, hi = lo + NODE_RANGE;
        const int e0 = chunk * FILL_CHUNK + t * 8;
        if (e0 >= N_EDGES) return;
        const int4 d0 = *(const int4*)&dst[e0];
        const int4 d1 = *(const int4*)&dst[e0 + 4];
        const int dd[8] = {d0.x, d0.y, d0.z, d0.w, d1.x, d1.y, d1.z, d1.w};
#pragma unroll
        for (int i = 0; i < 8; i++) {
            int d = dd[i];
            if (d < lo || d >= hi) continue;
            int e = e0 + i;
            int slot = atomicAdd(&cnt[d], 1);
            if (slot < CAP) {
                unsigned int iw = (unsigned int)(ewt[e] * 32767.f + 0.5f);
                bucket[d * CAP + slot] = ((unsigned int)src[e] << 15) | iw;
            }
        }
        return;
    }
    if (blockIdx.x < W2P0) {
        const int w = t >> 6, lane = t & 63;
#pragma unroll
        for (int dd = 0; dd < 4; dd++) {
            int dot = w + dd * 4;
            int k = dot & 7;
            const float* a = (dot < 8) ? a1s : a1d;
            float v = W1[k * NHID + lane] * a[lane] + W1[k * NHID + 64 + lane] * a[64 + lane];
#pragma unroll
            for (int off = 32; off > 0; off >>= 1) v += __shfl_down(v, off);
            if (lane == 0) sw[dot] = v;
        }
        __syncthreads();
        const int i = (blockIdx.x - FSFD0) * 256 + t;
        if (i < N_NODES) {
            const float4 x0 = ((const float4*)x)[i * 2];
            const float4 x1 = ((const float4*)x)[i * 2 + 1];
            float fsv = x0.x*sw[0] + x0.y*sw[1] + x0.z*sw[2] + x0.w*sw[3]
                      + x1.x*sw[4] + x1.y*sw[5] + x1.z*sw[6] + x1.w*sw[7];
            float fdv = x0.x*sw[8] + x0.y*sw[9] + x0.z*sw[10] + x0.w*sw[11]
                      + x1.x*sw[12] + x1.y*sw[13] + x1.z*sw[14] + x1.w*sw[15];
            float4* xr = (float4*)&xf[(size_t)i * 16];
            xr[0] = x0;
            xr[1] = x1;
            xr[2] = make_float4(fsv, fdv, 0.f, 0.f);
        }
        return;
    }
    if (blockIdx.x < W2T0) {
        const int k = (blockIdx.x - W2P0) * 2 + (t >> 7);
        const int n = t & 127;
        float wv = W2[k * NHID + n];
        float vs = wv * a2s[n], vd = wv * a2d[n];
#pragma unroll
        for (int off = 32; off > 0; off >>= 1) { vs += __shfl_down(vs, off); vd += __shfl_down(vd, off); }
        const int wid = t >> 6;
        if ((t & 63) == 0) { ps[wid] = vs; pd[wid] = vd; }
        __syncthreads();
        if ((t & 127) == 0) { w2s[k] = ps[wid] + ps[wid + 1]; w2d[k] = pd[wid] + pd[wid + 1]; }
        return;
    }
    if (blockIdx.x < WGT0) {
        const int n = (blockIdx.x - W2T0) * 4 + (t >> 6);
        const int k2 = (t & 63) * 2;
        *(unsigned int*)&W2t[n * 128 + k2] = pack_bf2(W2[k2 * NHID + n], W2[(k2 + 1) * NHID + n]);
        return;
    }
    const int n = (blockIdx.x - WGT0) * 4 + (t >> 6);
    const int k2 = (t & 63) * 2;
    *(unsigned int*)&Wgt[n * 128 + k2] = pack_bf2(Wg[k2 * NCLASS + n], Wg[(k2 + 1) * NCLASS + n]);
}

// ===== sort + gather + y1 + BN partials, grid-strided 3200 x 4 iters =====
// Gather reads the packed xf row: ONE 64B line per edge ({x8, fs, fd}).
__global__ __launch_bounds__(256)
void k_sort_gather_y1(const int* __restrict__ cnt, unsigned int* __restrict__ bucket,
                      const float* __restrict__ xf, const float* __restrict__ W1,
                      bf16* __restrict__ y1,
                      float* __restrict__ Psum, float* __restrict__ Psq) {
    const int xcd = blockIdx.x & 7;
    const int wb  = blockIdx.x >> 3;
    const int t = threadIdx.x;
    const int q = t >> 6;
    const int lane = t & 63;
    float w1c0[8], w1c1[8];
#pragma unroll
    for (int k = 0; k < 8; k++) {
        const float2 wv = *(const float2*)&W1[k * NHID + 2 * lane];
        w1c0[k] = wv.x; w1c1[k] = wv.y;
    }
    float ls0 = 0.f, ls1 = 0.f, lq0 = 0.f, lq1 = 0.f;
    for (int it = 0; it < SG_IT; it++) {
        const int ni = (wb + it * 400) * 4 + q;
        if (ni >= NODE_RANGE) continue;
        const int d = xcd * NODE_RANGE + ni;
        const int deg = min(cnt[d], CAP);
        unsigned int v = (lane < deg) ? bucket[d * CAP + lane] : 0xFFFFFFFFu;
#pragma unroll
        for (int k = 2; k <= 64; k <<= 1) {
#pragma unroll
            for (int s = k >> 1; s > 0; s >>= 1) {
                unsigned int o = (unsigned int)__shfl_xor((int)v, s);
                bool keepmin = ((lane & s) == 0) == ((lane & k) == 0);
                v = keepmin ? min(v, o) : max(v, o);
            }
        }
        if (lane < deg) bucket[d * CAP + lane] = v;
        const int epair = lane >> 1;
        const int half  = lane & 1;
        const float fdd = xf[(size_t)d * 16 + 9];
        float4 acc = {0.f, 0.f, 0.f, 0.f};
        float den = 0.f;
        for (int base = 0; base < deg; base += 32) {
            int e = base + epair;
            unsigned int u = (unsigned int)__shfl((int)v, e);
            if (e < deg) {
                int s = u >> 15;
                const float4 xv = *(const float4*)&xf[(size_t)s * 16 + half * 4];
                float fsv = xf[(size_t)s * 16 + 8];       // same 64B line as xv
                float f = fsv + fdd;
                float lr = f > 0.f ? f : 0.2f * f;
                float c = __expf(-lr);
                if (half == 0) den += c;
                acc.x += c * xv.x; acc.y += c * xv.y; acc.z += c * xv.z; acc.w += c * xv.w;
            }
        }
#pragma unroll
        for (int off = 2; off < 64; off <<= 1) {
            acc.x += __shfl_xor(acc.x, off);
            acc.y += __shfl_xor(acc.y, off);
            acc.z += __shfl_xor(acc.z, off);
            acc.w += __shfl_xor(acc.w, off);
            den   += __shfl_xor(den, off);
        }
        den += __shfl_xor(den, 1);
        float4 oth;
        oth.x = __shfl_xor(acc.x, 1);
        oth.y = __shfl_xor(acc.y, 1);
        oth.z = __shfl_xor(acc.z, 1);
        oth.w = __shfl_xor(acc.w, 1);
        const float r = 1.f / (den + SEG_EPS);
        float xa[8];
        if ((lane & 1) == 0) {
            xa[0]=acc.x*r; xa[1]=acc.y*r; xa[2]=acc.z*r; xa[3]=acc.w*r;
            xa[4]=oth.x*r; xa[5]=oth.y*r; xa[6]=oth.z*r; xa[7]=oth.w*r;
        } else {
            xa[0]=oth.x*r; xa[1]=oth.y*r; xa[2]=oth.z*r; xa[3]=oth.w*r;
            xa[4]=acc.x*r; xa[5]=acc.y*r; xa[6]=acc.z*r; xa[7]=acc.w*r;
        }
        float v0 = 0.f, v1 = 0.f;
#pragma unroll
        for (int k = 0; k < 8; k++) {
            v0 += xa[k] * w1c0[k];
            v1 += xa[k] * w1c1[k];
        }
        ((unsigned int*)y1)[(size_t)d * 64 + lane] = pack_bf2(v0, v1);
        ls0 += v0; lq0 += v0 * v0;
        ls1 += v1; lq1 += v1 * v1;
    }
    __shared__ float sred[4][64][2];
    sred[q][lane][0] = ls0;
    sred[q][lane][1] = ls1;
    __syncthreads();
    if (t < 128) {
        int ln = t >> 1, cp = t & 1;
        Psum[blockIdx.x * 128 + t] =
            ((sred[0][ln][cp] + sred[1][ln][cp]) + sred[2][ln][cp]) + sred[3][ln][cp];
    }
    __syncthreads();
    sred[q][lane][0] = lq0;
    sred[q][lane][1] = lq1;
    __syncthreads();
    if (t < 128) {
        int ln = t >> 1, cp = t & 1;
        Psq[blockIdx.x * 128 + t] =
            ((sred[0][ln][cp] + sred[1][ln][cp]) + sred[2][ln][cp]) + sred[3][ln][cp];
    }
}

// ===== fused BN reduction: 16 workers + 1 spin-wait finalizer =====
__global__ __launch_bounds__(256)
void k_reduce_fused(const float* __restrict__ Psum, const float* __restrict__ Psq,
                    int nIn, int chunk,
                    float* __restrict__ Qsum, float* __restrict__ Qsq,
                    const float* __restrict__ gamma, const float* __restrict__ beta,
                    float* __restrict__ scale, float* __restrict__ shift,
                    int* __restrict__ flag) {
    const int t = threadIdx.x;
    if (blockIdx.x < 16) {
        const int j = t & 127;
        const int h = t >> 7;
        const int u = blockIdx.x * 2 + h;
        const int b0 = u * chunk, b1 = min(b0 + chunk, nIn);
        float s = 0.f, q = 0.f;
#pragma unroll 8
        for (int b = b0; b < b1; b++) {
            s += Psum[b * 128 + j];
            q += Psq[b * 128 + j];
        }
        Qsum[u * 128 + j] = s;
        Qsq[u * 128 + j] = q;
        __threadfence();
        __syncthreads();
        if (t == 0) atomicAdd(flag, 1);
        return;
    }
    if (t == 0) { while (atomicAdd(flag, 0) < 16) { } }
    __syncthreads();
    __threadfence();
    const int j = t & 127;
    const int g = t >> 7;
    float s = 0.f, q = 0.f;
#pragma unroll
    for (int u = g * 16; u < g * 16 + 16; u++) {
        s += Qsum[u * 128 + j];
        q += Qsq[u * 128 + j];
    }
    __shared__ float Ls[2][128], Lq[2][128];
    Ls[g][j] = s; Lq[g][j] = q;
    __syncthreads();
    if (g == 0) {
        float st = Ls[0][j] + Ls[1][j];
        float qt = Lq[0][j] + Lq[1][j];
        float mu = st * (1.f / N_NODES);
        float var = qt * (1.f / N_NODES) - mu * mu;
        float rs = rsqrtf(var + BN_EPS);
        float ga = gamma[j];
        scale[j] = rs * ga;
        shift[j] = beta[j] - mu * rs * ga;
    }
    __syncthreads();
    if (t == 0) atomicExch(flag, 0);
}

// ===== MFMA GEMM v2: direct-A from global, prestaged bf16 B =====
template<int NCV, bool ATT>
__global__ __launch_bounds__(256)
void k_gemm_mfma(const bf16* __restrict__ Yin,
                 const float* __restrict__ scale, const float* __restrict__ shift,
                 const bf16* __restrict__ Wt_g,
                 bf16* __restrict__ hout,
                 const float* __restrict__ w2s, const float* __restrict__ w2d,
                 float* __restrict__ fs, float* __restrict__ fd) {
    constexpr int NT = NCV / 16;
    __shared__ bf16 Wt[NCV * 136];
    __shared__ float scb[128], shb[128];
    const int t = threadIdx.x;
    for (int idx = t; idx < NCV * 16; idx += 256) {
        int n = idx >> 4, c = idx & 15;
        *(u32x4*)&Wt[n * 136 + c * 8] = *(const u32x4*)&Wt_g[n * 128 + c * 8];
    }
    if (t < 128) { scb[t] = scale[t]; shb[t] = shift[t]; }
    const int lane = t & 63;
    const int m16 = lane & 15;
    const int g = lane >> 4;
    const int rg = t >> 6;
    short8 attb[4];
    if constexpr (ATT) {
#pragma unroll
        for (int kk = 0; kk < 4; kk++) {
            union { short8 s; unsigned int u[4]; } pk;
            if (m16 < 2) {
                const float* wv = (m16 == 0) ? w2s : w2d;
                const float4 f0 = *(const float4*)&wv[kk * 32 + g * 8];
                const float4 f1 = *(const float4*)&wv[kk * 32 + g * 8 + 4];
                pk.u[0] = pack_bf2(f0.x, f0.y);
                pk.u[1] = pack_bf2(f0.z, f0.w);
                pk.u[2] = pack_bf2(f1.x, f1.y);
                pk.u[3] = pack_bf2(f1.z, f1.w);
            } else {
                pk.u[0] = pk.u[1] = pk.u[2] = pk.u[3] = 0u;
            }
            attb[kk] = pk.s;
        }
    }
    __syncthreads();

    const int row0 = blockIdx.x * 64;
    const int arow = row0 + rg * 16 + m16;
    const bool rok = arow < N_NODES;
    f32x4 acc[NT];
#pragma unroll
    for (int c = 0; c < NT; c++) acc[c] = (f32x4){0.f, 0.f, 0.f, 0.f};
    f32x4 accA = (f32x4){0.f, 0.f, 0.f, 0.f};
#pragma unroll
    for (int kk = 0; kk < 4; kk++) {
        u32x4 u4 = rok
            ? *(const u32x4*)&((const unsigned int*)Yin)[(size_t)arow * 64 + kk * 16 + g * 4]
            : (u32x4){0u, 0u, 0u, 0u};
        const float4 s0 = *(const float4*)&scb[kk * 32 + g * 8];
        const float4 s1 = *(const float4*)&scb[kk * 32 + g * 8 + 4];
        const float4 h0 = *(const float4*)&shb[kk * 32 + g * 8];
        const float4 h1 = *(const float4*)&shb[kk * 32 + g * 8 + 4];
        const float scv[8] = {s0.x, s0.y, s0.z, s0.w, s1.x, s1.y, s1.z, s1.w};
        const float shv[8] = {h0.x, h0.y, h0.z, h0.w, h1.x, h1.y, h1.z, h1.w};
        union { short8 s; unsigned int u[4]; } A;
#pragma unroll
        for (int fq = 0; fq < 4; fq++) {
            unsigned int u = u4[fq];
            float v0 = bfbits2f(u & 0xFFFF) * scv[2*fq]   + shv[2*fq];   v0 = v0 > 0.f ? v0 : 0.01f * v0;
            float v1 = bfbits2f(u >> 16)    * scv[2*fq+1] + shv[2*fq+1]; v1 = v1 > 0.f ? v1 : 0.01f * v1;
            A.u[fq] = pack_bf2(v0, v1);
        }
#pragma unroll
        for (int c = 0; c < NT; c++) {
            short8 bfr = *(const short8*)&Wt[(c * 16 + m16) * 136 + kk * 32 + g * 8];
            acc[c] = __builtin_amdgcn_mfma_f32_16x16x32_bf16(A.s, bfr, acc[c], 0, 0, 0);
        }
        if constexpr (ATT)
            accA = __builtin_amdgcn_mfma_f32_16x16x32_bf16(A.s, attb[kk], accA, 0, 0, 0);
    }
    const int orow = row0 + rg * 16 + g * 4;
#pragma unroll
    for (int c = 0; c < NT; c++) {
#pragma unroll
        for (int r = 0; r < 4; r++) {
            int grow = orow + r;
            if (grow < N_NODES)
                hout[(size_t)grow * 128 + c * 16 + m16] = __float2bfloat16(acc[c][r]);
        }
    }
    if constexpr (ATT) {
        if (m16 < 2) {
            float* o = (m16 == 0) ? fs : fd;
#pragma unroll
            for (int r = 0; r < 4; r++) {
                int grow = orow + r;
                if (grow < N_NODES) o[grow] = accA[r];
            }
        }
    }
}

// ===== attention gather, 4-edges-per-wave dwordx4 + fused BN stats =====
__global__ __launch_bounds__(256)
void k_gather_attn_bf(const int* __restrict__ cnt, const unsigned int* __restrict__ bucket,
                      const float* __restrict__ fs, const float* __restrict__ fd,
                      const bf16* __restrict__ h, bf16* __restrict__ y,
                      float* __restrict__ Psum, float* __restrict__ Psq) {
    const int xcd = blockIdx.x & 7;
    const int wb  = blockIdx.x >> 3;
    const int t = threadIdx.x;
    const int q = t >> 6;
    const int lane = t & 63;
    const int grp = lane >> 4;
    const int l = lane & 15;
    __shared__ int s_idx[4][CAP];
    __shared__ float s_e[4][CAP];
    __shared__ float sred[4][16][8];
    float ls[8], lq[8];
#pragma unroll
    for (int i = 0; i < 8; i++) { ls[i] = 0.f; lq[i] = 0.f; }

    for (int it = 0; it < ATT_IT; it++) {
        const int ni = (wb + it * 400) * 4 + q;
        if (ni >= NODE_RANGE) continue;
        const int d = xcd * NODE_RANGE + ni;
        const int deg = min(cnt[d], CAP);
        const float fdd = fd[d];
        if (lane < deg) {
            int s = bucket[d * CAP + lane] >> 15;
            float f = fs[s] + fdd;
            float lr = f > 0.f ? f : 0.2f * f;
            s_idx[q][lane] = s;
            s_e[q][lane] = __expf(-lr);
        }
        float a[8];
#pragma unroll
        for (int i = 0; i < 8; i++) a[i] = 0.f;
        float den = 0.f;
#pragma unroll 4
        for (int base = 0; base < deg; base += 4) {
            int k = base + grp;
            bool ev = k < deg;
            int kk = ev ? k : 0;
            float e = ev ? s_e[q][kk] : 0.f;
            int sidx = s_idx[q][kk];
            u32x4 u4 = *(const u32x4*)&((const unsigned int*)h)[(size_t)sidx * 64 + l * 4];
            den += e;
#pragma unroll
            for (int fq = 0; fq < 4; fq++) {
                unsigned int u = u4[fq];
                a[2*fq]   += e * bfbits2f(u & 0xFFFF);
                a[2*fq+1] += e * bfbits2f(u >> 16);
            }
        }
#pragma unroll
        for (int off = 16; off < 64; off <<= 1) {
#pragma unroll
            for (int i = 0; i < 8; i++) a[i] += __shfl_xor(a[i], off);
            den += __shfl_xor(den, off);
        }
        float r = 1.f / (den + SEG_EPS);
        if (lane < 16) {
            u32x4 pk;
#pragma unroll
            for (int fq = 0; fq < 4; fq++) {
                float v0 = a[2*fq] * r, v1 = a[2*fq+1] * r;
                pk[fq] = pack_bf2(v0, v1);
                ls[2*fq] += v0;   lq[2*fq] += v0 * v0;
                ls[2*fq+1] += v1; lq[2*fq+1] += v1 * v1;
            }
            *(u32x4*)&((unsigned int*)y)[(size_t)d * 64 + l * 4] = pk;
        }
    }
    if (lane < 16) {
#pragma unroll
        for (int i = 0; i < 8; i++) sred[q][l][i] = ls[i];
    }
    __syncthreads();
    if (t < 128) {
        int l16 = t >> 3, i8 = t & 7;
        Psum[blockIdx.x * 128 + t] =
            ((sred[0][l16][i8] + sred[1][l16][i8]) + sred[2][l16][i8]) + sred[3][l16][i8];
    }
    __syncthreads();
    if (lane < 16) {
#pragma unroll
        for (int i = 0; i < 8; i++) sred[q][l][i] = lq[i];
    }
    __syncthreads();
    if (t < 128) {
        int l16 = t >> 3, i8 = t & 7;
        Psq[blockIdx.x * 128 + t] =
            ((sred[0][l16][i8] + sred[1][l16][i8]) + sred[2][l16][i8]) + sred[3][l16][i8];
    }
}

// ===== final gather + epilogue: grid-strided 3200 x 4, 14-chunk loads =====
__global__ __launch_bounds__(256)
void k_gather_out_bf(const int* __restrict__ cnt, const unsigned int* __restrict__ bucket,
                     const bf16* __restrict__ sup, const float* __restrict__ bg,
                     float* __restrict__ out) {
    const int xcd = blockIdx.x & 7;
    const int wb  = blockIdx.x >> 3;
    const int t = threadIdx.x;
    const int q = t >> 6;
    const int lane = t & 63;
    const int grp = lane >> 4;
    const int l = lane & 15;
    __shared__ int s_idx[4][CAP];
    __shared__ float s_w[4][CAP];
    for (int it = 0; it < OUT_IT; it++) {
        const int ni = (wb + it * 400) * 4 + q;       // wave-uniform
        if (ni >= NODE_RANGE) continue;               // no barriers in loop
        const int d = xcd * NODE_RANGE + ni;
        const int deg = min(cnt[d], CAP);
        if (lane < deg) {
            unsigned int b = bucket[d * CAP + lane];
            s_idx[q][lane] = b >> 15;
            s_w[q][lane] = (float)(b & 0x7FFF) * (1.f / (32767.f * 3.f));
        }
        float a[8];
#pragma unroll
        for (int i = 0; i < 8; i++) a[i] = 0.f;
#pragma unroll 4
        for (int base = 0; base < deg; base += 4) {
            int k = base + grp;
            bool ev = k < deg;
            int kk = ev ? k : 0;
            float w = ev ? s_w[q][kk] : 0.f;
            int sidx = s_idx[q][kk];
            u32x4 u4 = (l < 14)    // chunks 14,15 are pad cols 112..127
                ? *(const u32x4*)&((const unsigned int*)sup)[(size_t)sidx * 64 + l * 4]
                : (u32x4){0u, 0u, 0u, 0u};
#pragma unroll
            for (int fq = 0; fq < 4; fq++) {
                unsigned int u = u4[fq];
                a[2*fq]   += w * bfbits2f(u & 0xFFFF);
                a[2*fq+1] += w * bfbits2f(u >> 16);
            }
        }
#pragma unroll
        for (int off = 16; off < 64; off <<= 1) {
#pragma unroll
            for (int i = 0; i < 8; i++) a[i] += __shfl_xor(a[i], off);
        }
        if (l < 14) {
            u32x4 us = *(const u32x4*)&((const unsigned int*)sup)[(size_t)d * 64 + l * 4];
            const float4 b0 = *(const float4*)&bg[l * 8];
            const float4 b1 = *(const float4*)&bg[l * 8 + 4];
            float4 o0, o1;
            o0.x = a[0] + bfbits2f(us[0] & 0xFFFF) * (2.f/3.f) + b0.x;
            o0.y = a[1] + bfbits2f(us[0] >> 16)    * (2.f/3.f) + b0.y;
            o0.z = a[2] + bfbits2f(us[1] & 0xFFFF) * (2.f/3.f) + b0.z;
            o0.w = a[3] + bfbits2f(us[1] >> 16)    * (2.f/3.f) + b0.w;
            o1.x = a[4] + bfbits2f(us[2] & 0xFFFF) * (2.f/3.f) + b1.x;
            o1.y = a[5] + bfbits2f(us[2] >> 16)    * (2.f/3.f) + b1.y;
            o1.z = a[6] + bfbits2f(us[3] & 0xFFFF) * (2.f/3.f) + b1.z;
            o1.w = a[7] + bfbits2f(us[3] >> 16)    * (2.f/3.f) + b1.w;
            *(float4*)&out[(size_t)d * NCLASS + l * 8]     = o0;
            *(float4*)&out[(size_t)d * NCLASS + l * 8 + 4] = o1;
        }
    }
}

extern "C" void kernel_launch(void* const* d_in, const int* in_sizes, int n_in,
                              void* d_out, int out_size, void* d_ws, size_t ws_size,
                              hipStream_t stream) {
    const float* x    = (const float*)d_in[0];
    const int*   ei   = (const int*)d_in[1];
    const float* ewt  = (const float*)d_in[2];
    const float* W1   = (const float*)d_in[3];
    const float* a1s  = (const float*)d_in[4];
    const float* a1d  = (const float*)d_in[5];
    const float* W2   = (const float*)d_in[6];
    const float* a2s  = (const float*)d_in[7];
    const float* a2d  = (const float*)d_in[8];
    const float* gam  = (const float*)d_in[9];
    const float* bet  = (const float*)d_in[10];
    const float* Wg   = (const float*)d_in[11];
    const float* bg   = (const float*)d_in[12];
    float* out = (float*)d_out;

    const int* src = ei;
    const int* dst = ei + N_EDGES;

    float* ws    = (float*)d_ws;
    bf16*  Yb    = (bf16*)ws;                       // [N,128] bf16 (y1, then y2)
    bf16*  Hb    = (bf16*)(ws + 3203072);           // [N,128] bf16 (h2 / support)
    unsigned int* bucket = (unsigned int*)(ws + 6403072);   // [N*64] packed
    float* fs    = ws + 10003072;                   // [N] (layer-2 att src proj)
    float* fd    = ws + 10053072;                   // [N] (layer-2 att dst proj)
    int*   cnt   = (int*)(ws + 10103072);           // [N]
    int*   flags = (int*)(ws + 10153072);           // [4] (covered by memset)
    float* scale = ws + 10153076;                   // [128]
    float* shift = scale + 128;                     // [128]
    float* w2s   = shift + 128;                     // [128]
    float* w2d   = w2s + 128;                       // [128] ends 10153588
    float* Psum  = ws + 10153600;                   // [3200][128]
    float* Psq   = Psum + 409600;                   // [3200][128]
    float* Qsum  = Psq + 409600;                    // [32][128]
    float* Qsq   = Qsum + 4096;                     // [32][128]
    bf16*  W2t   = (bf16*)(Qsq + 4096);             // [128][128] bf16 (8192 f)
    bf16*  Wgt   = W2t + 16384;                     // [112][128] bf16 (7168 f)
    float* xf    = ws + 10996352;                   // [N][16] packed {x8,fs,fd,pad}
                                                    // 64B-aligned; ends 11796352 (47.2MB)

    // ---- bucketed CSR build + fsfd(packed xf) + weight prep (one launch) ----
    hipMemsetAsync(cnt, 0, (size_t)(N_NODES + 4) * 4, stream);   // cnt + flags
    k_fill_fsfd<<<GRID_FILL, 256, 0, stream>>>(
        src, dst, ewt, cnt, bucket, x, W1, a1s, a1d, xf,
        W2, a2s, a2d, w2s, w2d, Wg, W2t, Wgt);

    // ---- layer 1 ----
    k_sort_gather_y1<<<SG_GRID, 256, 0, stream>>>(cnt, bucket, xf, W1,
                                                  Yb, Psum, Psq);
    k_reduce_fused<<<17, 256, 0, stream>>>(Psum, Psq, SG_GRID, 100, Qsum, Qsq,
                                           gam, bet, scale, shift, flags + 0);

    // ---- layer 2 ----
    k_gemm_mfma<128, true><<<MACRO_TILES, 256, 0, stream>>>(Yb, scale, shift, W2t, Hb,
                                                            w2s, w2d, fs, fd);    // Hb = h2
    k_gather_attn_bf<<<ATT_GRID, 256, 0, stream>>>(cnt, bucket, fs, fd, Hb, Yb,
                                                   Psum, Psq);                    // Yb = y2 + stats
    k_reduce_fused<<<17, 256, 0, stream>>>(Psum, Psq, ATT_GRID, 100, Qsum, Qsq,
                                           gam, bet, scale, shift, flags + 1);

    // ---- output head ----
    k_gemm_mfma<112, false><<<MACRO_TILES, 256, 0, stream>>>(Yb, scale, shift, Wgt, Hb,
                                                             nullptr, nullptr, nullptr, nullptr);
    k_gather_out_bf<<<OUT_GRID, 256, 0, stream>>>(cnt, bucket, Hb, bg, out);
}